// Round 10
// baseline (169.048 us; speedup 1.0000x reference)
//
#include <hip/hip_runtime.h>
#include <math.h>

#define NB 8
#define NHH 32
#define NWW 32
#define NC 384
#define NHEAD 12
#define NHD 32
#define NN1 1025
#define NHW 1024
#define NMROWS (NB * NN1)   /* 8200 */
#define MPAD 8320           /* padded M for 64-row tiles (130 tiles) */
#define VSTRIDE 1088        /* vT row stride: 2176B = 17 x 128B lines */

typedef float f32x4 __attribute__((ext_vector_type(4)));
typedef __bf16 bf16x8 __attribute__((ext_vector_type(8)));

static __device__ __forceinline__ bf16x8 as_bf16x8(uint4 u) {
    union { uint4 a; bf16x8 b; } x; x.a = u; return x.b;
}
static __device__ __forceinline__ unsigned short bfbits(__bf16 b) {
    union { __bf16 a; unsigned short s; } u; u.a = b; return u.s;
}
static __device__ __forceinline__ float bf2f(unsigned short s) {
    union { unsigned u; float f; } x; x.u = ((unsigned)s) << 16; return x.f;
}
static __device__ __forceinline__ unsigned pack2(float a, float b) {
    return (unsigned)bfbits((__bf16)a) | ((unsigned)bfbits((__bf16)b) << 16);
}
// bijective XCD swizzle (m204): hw block i -> work id, contiguous per XCD
static __device__ __forceinline__ int xcd_swz(int i, int nwg) {
    int xcd = i & 7, pos = i >> 3;
    int q = nwg >> 3, r = nwg & 7;
    return xcd * q + (xcd < r ? xcd : r) + pos;
}

// ---------------------------------------------------------------------------
// Kernel 0: prep — convert A=concat(cls,x) to bf16 [8320][384] (zero pad),
// qkv_w / proj_w to bf16, transpose lepe_w to [25][384] f32, zero ao pad rows.
// ---------------------------------------------------------------------------
#define P_N1 798720   /* A convert, 4-wide   */
#define P_N2 110592   /* wq convert, 4-wide  */
#define P_N3 36864    /* wp convert, 4-wide  */
#define P_N4 9600     /* lepeT scalar        */
#define P_N5 11520    /* ao pad zero, 4-wide */
#define P_TOT (P_N1 + P_N2 + P_N3 + P_N4 + P_N5)

__global__ __launch_bounds__(256) void prep_k(
    const float* __restrict__ x, const float* __restrict__ cls,
    const float* __restrict__ qkv_w, const float* __restrict__ proj_w,
    const float* __restrict__ lepe_w,
    __bf16* __restrict__ Ab, __bf16* __restrict__ wqb, __bf16* __restrict__ wpb,
    float* __restrict__ lepeT, __bf16* __restrict__ aob)
{
    int idx = blockIdx.x * 256 + threadIdx.x;
    if (idx >= P_TOT) return;
    if (idx < P_N1) {
        int e0 = idx * 4;
        int m = e0 / NC, kk = e0 % NC;
        float4 v = make_float4(0.f, 0.f, 0.f, 0.f);
        if (m < NMROWS) {
            int b = m / NN1, n = m % NN1;
            const float* src = (n == 0) ? (cls + (size_t)b * NC + kk)
                                        : (x + ((size_t)(b * NHW + (n - 1))) * NC + kk);
            v = *(const float4*)src;
        }
        uint2 u; u.x = pack2(v.x, v.y); u.y = pack2(v.z, v.w);
        *(uint2*)(Ab + (size_t)m * NC + kk) = u;
        return;
    }
    idx -= P_N1;
    if (idx < P_N2) {
        int e0 = idx * 4;
        float4 v = *(const float4*)(qkv_w + e0);
        uint2 u; u.x = pack2(v.x, v.y); u.y = pack2(v.z, v.w);
        *(uint2*)(wqb + e0) = u;
        return;
    }
    idx -= P_N2;
    if (idx < P_N3) {
        int e0 = idx * 4;
        float4 v = *(const float4*)(proj_w + e0);
        uint2 u; u.x = pack2(v.x, v.y); u.y = pack2(v.z, v.w);
        *(uint2*)(wpb + e0) = u;
        return;
    }
    idx -= P_N3;
    if (idx < P_N4) {
        int tap = idx / NC, cc = idx % NC;
        lepeT[tap * NC + cc] = lepe_w[cc * 25 + tap];
        return;
    }
    idx -= P_N4;
    {   // zero ao pad rows 8200..8319
        uint2 z; z.x = 0; z.y = 0;
        *(uint2*)(aob + (size_t)NMROWS * NC + idx * 4) = z;
    }
}

#define LP 72     /* LDS row stride elems (144B) */
#define QSCALE 0.25505654007f   /* 1/sqrt(32) * log2(e) */
#define CPD 136   /* C staging row stride (272B, 16B-aligned) */

// ---------------------------------------------------------------------------
// QKV GEMM: 64x128 tile (M x N), BK=64, 4 waves as 2x2 of 32x64 sub-tiles.
// Grid = 130 m-tiles x 9 n-tiles = 1170 blocks (~4.6 blocks/CU for TLP).
// Epilogue stages C tile in LDS, then coalesced/transposed write-out.
// ---------------------------------------------------------------------------
union QkvSm {
    struct { __bf16 As[64][LP]; __bf16 Bs[128][LP]; } g;
    __bf16 C[64][CPD];
};

__global__ __launch_bounds__(256) void qkv_mfma_k(
    const __bf16* __restrict__ A, const __bf16* __restrict__ W,
    __bf16* __restrict__ qg, __bf16* __restrict__ kg, __bf16* __restrict__ vT)
{
    __shared__ QkvSm sm;
    const int tid  = threadIdx.x;
    const int lane = tid & 63;
    const int wid  = tid >> 6;
    const int wr   = wid >> 1, wc = wid & 1;
    const int c    = lane & 15, hg = lane >> 4;
    const int wg   = xcd_swz(blockIdx.x, 9 * 130);
    const int tile = wg % 9;            // 0-2: q, 3-5: k, 6-8: v
    const int m0   = (wg / 9) * 64;
    const int n0   = tile * 128;
    const int which = tile / 3;
    const int tseg  = tile % 3;

    const int arow = tid >> 2, acol = (tid & 3) * 16;   // 2 uint4 / thread
    const int brow = tid >> 1, bcol = (tid & 1) * 32;   // 4 uint4 / thread

    f32x4 acc[2][4];
#pragma unroll
    for (int i = 0; i < 2; ++i)
#pragma unroll
        for (int j = 0; j < 4; ++j) acc[i][j] = f32x4{0.f, 0.f, 0.f, 0.f};

    uint4 a4[2], b4[4];
#pragma unroll
    for (int s = 0; s < 2; ++s)
        a4[s] = *(const uint4*)(A + (size_t)(m0 + arow) * NC + acol + s * 8);
#pragma unroll
    for (int s = 0; s < 4; ++s)
        b4[s] = *(const uint4*)(W + (size_t)(n0 + brow) * NC + bcol + s * 8);

    for (int k0 = 0; k0 < NC; k0 += 64) {
        __syncthreads();
#pragma unroll
        for (int s = 0; s < 2; ++s) *(uint4*)&sm.g.As[arow][acol + s * 8] = a4[s];
#pragma unroll
        for (int s = 0; s < 4; ++s) *(uint4*)&sm.g.Bs[brow][bcol + s * 8] = b4[s];
        __syncthreads();
        if (k0 + 64 < NC) {   // prefetch next K-step while MFMAs run
#pragma unroll
            for (int s = 0; s < 2; ++s)
                a4[s] = *(const uint4*)(A + (size_t)(m0 + arow) * NC + k0 + 64 + acol + s * 8);
#pragma unroll
            for (int s = 0; s < 4; ++s)
                b4[s] = *(const uint4*)(W + (size_t)(n0 + brow) * NC + k0 + 64 + bcol + s * 8);
        }
#pragma unroll
        for (int ks = 0; ks < 2; ++ks) {
            bf16x8 af[2], bfr[4];
#pragma unroll
            for (int i = 0; i < 2; ++i)
                af[i] = as_bf16x8(*(const uint4*)&sm.g.As[wr * 32 + i * 16 + c][ks * 32 + hg * 8]);
#pragma unroll
            for (int j = 0; j < 4; ++j)
                bfr[j] = as_bf16x8(*(const uint4*)&sm.g.Bs[wc * 64 + j * 16 + c][ks * 32 + hg * 8]);
#pragma unroll
            for (int i = 0; i < 2; ++i)
#pragma unroll
                for (int j = 0; j < 4; ++j)
                    acc[i][j] = __builtin_amdgcn_mfma_f32_16x16x32_bf16(
                        af[i], bfr[j], acc[i][j], 0, 0, 0);
        }
    }

    __syncthreads();   // done with As/Bs; reuse as C staging
    const float qs = (which == 0) ? QSCALE : 1.0f;
#pragma unroll
    for (int i = 0; i < 2; ++i)
#pragma unroll
        for (int r = 0; r < 4; ++r) {
            int row = wr * 32 + i * 16 + 4 * hg + r;
#pragma unroll
            for (int j = 0; j < 4; ++j)
                sm.C[row][wc * 64 + j * 16 + c] = (__bf16)(acc[i][j][r] * qs);
        }
    __syncthreads();

    if (which < 2) {
        // q/k: row-major [bh][n][32], coalesced 16B stores (4 iters)
        __bf16* dstbase = (which == 0) ? qg : kg;
#pragma unroll
        for (int it = 0; it < 4; ++it) {
            int idx   = it * 256 + tid;       // 0..1023
            int headl = idx >> 8;             // 0..3
            int idx2  = idx & 255;
            int row   = idx2 >> 2;            // 0..63
            int chunk = idx2 & 3;
            int m = m0 + row;
            if (m < NMROWS) {
                int b = m / NN1, n = m % NN1;
                int h = tseg * 4 + headl;
                uint4 u = *(const uint4*)&sm.C[row][headl * 32 + chunk * 8];
                *(uint4*)(dstbase + ((size_t)(b * NHEAD + h) * NN1 + n) * NHD + chunk * 8) = u;
            }
        }
    } else {
        // v: transposed vT[(b*12+h)*32+d][n] from LDS column reads (4 iters)
        const unsigned short* CS = (const unsigned short*)&sm.C[0][0];
#pragma unroll
        for (int it = 0; it < 4; ++it) {
            int idx     = it * 256 + tid;        // 0..1023
            int row_out = idx & 127;             // headl*32 + d
            int span    = idx >> 7;              // 0..7 (8 n-values each)
            int h  = tseg * 4 + (row_out >> 5);
            int d  = row_out & 31;
            int mb = m0 + span * 8;
            int b0 = mb / NN1;
            if (mb + 7 < NMROWS && (mb + 7) / NN1 == b0) {
                int n = mb - b0 * NN1;
                unsigned short e[8];
#pragma unroll
                for (int u = 0; u < 8; ++u)
                    e[u] = CS[(span * 8 + u) * CPD + row_out];
                uint4 o;
                o.x = (unsigned)e[0] | ((unsigned)e[1] << 16);
                o.y = (unsigned)e[2] | ((unsigned)e[3] << 16);
                o.z = (unsigned)e[4] | ((unsigned)e[5] << 16);
                o.w = (unsigned)e[6] | ((unsigned)e[7] << 16);
                *(uint4*)(vT + ((size_t)(b0 * NHEAD + h) * NHD + d) * VSTRIDE + n) = o;
            } else {
#pragma unroll
                for (int u = 0; u < 8; ++u) {
                    int m = mb + u;
                    if (m >= NMROWS) continue;
                    int b = m / NN1, n = m % NN1;
                    vT[((size_t)(b * NHEAD + h) * NHD + d) * VSTRIDE + n]
                        = sm.C[span * 8 + u][row_out];
                }
            }
        }
    }
}

// ---------------------------------------------------------------------------
// proj GEMM: 128x64 tile (grid 390 blocks), 4 waves as 2x2 of 64x32,
// register-prefetched K-loop.
// ---------------------------------------------------------------------------
__global__ __launch_bounds__(256) void proj_mfma_k(
    const __bf16* __restrict__ A, const __bf16* __restrict__ W,
    const float* __restrict__ bias, float* __restrict__ out)
{
    __shared__ __bf16 As[128][LP];
    __shared__ __bf16 Bs[64][LP];
    const int tid  = threadIdx.x;
    const int lane = tid & 63;
    const int wid  = tid >> 6;
    const int wr   = wid >> 1, wc = wid & 1;
    const int c    = lane & 15, hg = lane >> 4;
    const int wg   = xcd_swz(blockIdx.x, 6 * 65);
    const int m0   = (wg / 6) * 128;
    const int n0   = (wg % 6) * 64;
    const int srow = tid >> 1;
    const int scol = (tid & 1) * 32;
    const int brow = tid >> 2;
    const int bcol = (tid & 3) * 16;

    f32x4 acc[4][2];
#pragma unroll
    for (int i = 0; i < 4; ++i)
#pragma unroll
        for (int j = 0; j < 2; ++j) acc[i][j] = f32x4{0.f, 0.f, 0.f, 0.f};

    uint4 a4[4], b4[2];
#pragma unroll
    for (int s = 0; s < 4; ++s)
        a4[s] = *(const uint4*)(A + (size_t)(m0 + srow) * NC + scol + s * 8);
#pragma unroll
    for (int s = 0; s < 2; ++s)
        b4[s] = *(const uint4*)(W + (size_t)(n0 + brow) * NC + bcol + s * 8);

    for (int k0 = 0; k0 < NC; k0 += 64) {
        __syncthreads();
#pragma unroll
        for (int s = 0; s < 4; ++s) *(uint4*)&As[srow][scol + s * 8] = a4[s];
#pragma unroll
        for (int s = 0; s < 2; ++s) *(uint4*)&Bs[brow][bcol + s * 8] = b4[s];
        __syncthreads();
        if (k0 + 64 < NC) {
#pragma unroll
            for (int s = 0; s < 4; ++s)
                a4[s] = *(const uint4*)(A + (size_t)(m0 + srow) * NC + k0 + 64 + scol + s * 8);
#pragma unroll
            for (int s = 0; s < 2; ++s)
                b4[s] = *(const uint4*)(W + (size_t)(n0 + brow) * NC + k0 + 64 + bcol + s * 8);
        }
#pragma unroll
        for (int ks = 0; ks < 2; ++ks) {
            bf16x8 af[4], bfr[2];
#pragma unroll
            for (int i = 0; i < 4; ++i)
                af[i] = as_bf16x8(*(const uint4*)&As[wr * 64 + i * 16 + c][ks * 32 + hg * 8]);
#pragma unroll
            for (int j = 0; j < 2; ++j)
                bfr[j] = as_bf16x8(*(const uint4*)&Bs[wc * 32 + j * 16 + c][ks * 32 + hg * 8]);
#pragma unroll
            for (int i = 0; i < 4; ++i)
#pragma unroll
                for (int j = 0; j < 2; ++j)
                    acc[i][j] = __builtin_amdgcn_mfma_f32_16x16x32_bf16(
                        af[i], bfr[j], acc[i][j], 0, 0, 0);
        }
    }

#pragma unroll
    for (int i = 0; i < 4; ++i)
#pragma unroll
        for (int r = 0; r < 4; ++r) {
            int m = m0 + wr * 64 + i * 16 + 4 * hg + r;
            if (m >= NMROWS) continue;
            int b = m / NN1, n = m % NN1;
            float* dstrow = (n == 0)
                ? (out + (size_t)NB * NHW * NC + (size_t)b * NC)
                : (out + ((size_t)(b * NHW) + (n - 1)) * NC);
#pragma unroll
            for (int j = 0; j < 2; ++j) {
                int col = n0 + wc * 32 + j * 16 + c;
                dstrow[col] = acc[i][j][r] + bias[col];
            }
        }
}

// ---------------------------------------------------------------------------
// Kernel 2: bf16-MFMA flash attention, double-buffered K/V, fixed-shift
// softmax, V staged directly from vT, s_setprio around MFMA clusters.
// ---------------------------------------------------------------------------
#define KC 64
#define KPAD 40
#define VPAD 72
#define PPAD 72
#define NCH ((NN1 + KC - 1) / KC)   /* 17 */

__global__ __launch_bounds__(256) void attn_mfma_k(
    const __bf16* __restrict__ qg, const __bf16* __restrict__ kg,
    const __bf16* __restrict__ vTg, __bf16* __restrict__ ao)
{
    __shared__ unsigned short Ks[2][KC][KPAD];   // [buf][key][d]
    __shared__ unsigned short Vs[2][32][VPAD];   // [buf][d][key]
    __shared__ unsigned short Ps[4][32][PPAD];   // per wave [q][key]

    const int wg    = xcd_swz(blockIdx.x, 9 * NB * NHEAD);
    const int qtile = wg % 9;
    const int bh    = wg / 9;
    const int b     = bh / NHEAD;
    const int hh    = bh % NHEAD;
    const int tid   = threadIdx.x;
    const int wv    = tid >> 6;
    const int lane  = tid & 63;
    const int c     = lane & 15;
    const int hg    = lane >> 4;
    const int q0    = qtile * 128 + wv * 32;

    const __bf16* qb = qg + (size_t)bh * NN1 * NHD;
    const __bf16* kb = kg + (size_t)bh * NN1 * NHD;
    const __bf16* vb = vTg + (size_t)bh * NHD * VSTRIDE;

    uint4 zero4 = make_uint4(0, 0, 0, 0);
    bf16x8 qf[2];
#pragma unroll
    for (int qt = 0; qt < 2; ++qt) {
        int row = q0 + qt * 16 + c;
        uint4 u = (row < NN1) ? *(const uint4*)(qb + (size_t)row * NHD + hg * 8)
                              : zero4;
        qf[qt] = as_bf16x8(u);
    }

    f32x4 O[2][2];
#pragma unroll
    for (int qt = 0; qt < 2; ++qt)
#pragma unroll
        for (int dt = 0; dt < 2; ++dt) O[qt][dt] = f32x4{0.f, 0.f, 0.f, 0.f};
    float lrun[2] = {0.f, 0.f};

    const int k_row = tid >> 2;
    const int k_col = (tid & 3) * 8;
    const int v_d   = tid >> 3;
    const int v_kq  = (tid & 7) * 8;

    uint4 kr = *(const uint4*)(kb + (size_t)k_row * NHD + k_col);
    uint4 vr = *(const uint4*)(vb + (size_t)v_d * VSTRIDE + v_kq);
    *(uint4*)&Ks[0][k_row][k_col] = kr;
    *(uint4*)&Vs[0][v_d][v_kq] = vr;
    __syncthreads();

    for (int t = 0; t < NCH; ++t) {
        const int kt0 = t * KC;
        const int cur = t & 1;
        const bool haveNext = (t + 1 < NCH);
        if (haveNext) {
            int nk = kt0 + KC + k_row;
            kr = (nk < NN1) ? *(const uint4*)(kb + (size_t)nk * NHD + k_col) : zero4;
            vr = *(const uint4*)(vb + (size_t)v_d * VSTRIDE + kt0 + KC + v_kq);
        }
        const bool full = (kt0 + KC <= NN1);

        bf16x8 kf[4];
#pragma unroll
        for (int kt = 0; kt < 4; ++kt)
            kf[kt] = as_bf16x8(*(const uint4*)&Ks[cur][kt * 16 + c][hg * 8]);

#pragma unroll
        for (int qt = 0; qt < 2; ++qt) {
            f32x4 Sf[4];
            __builtin_amdgcn_s_setprio(1);
#pragma unroll
            for (int kt = 0; kt < 4; ++kt)
                Sf[kt] = __builtin_amdgcn_mfma_f32_16x16x32_bf16(
                    kf[kt], qf[qt], f32x4{0.f, 0.f, 0.f, 0.f}, 0, 0, 0);
            __builtin_amdgcn_s_setprio(0);

            if (!full) {   // zero pad keys (exp2(-3e38) == 0)
#pragma unroll
                for (int kt = 0; kt < 4; ++kt)
#pragma unroll
                    for (int r = 0; r < 4; ++r) {
                        int key = kt0 + kt * 16 + 4 * hg + r;
                        if (key >= NN1) Sf[kt][r] = -3.0e38f;
                    }
            }
            float psum = 0.f;
#pragma unroll
            for (int kt = 0; kt < 4; ++kt) {
                float p0 = exp2f(Sf[kt][0]);
                float p1 = exp2f(Sf[kt][1]);
                float p2 = exp2f(Sf[kt][2]);
                float p3 = exp2f(Sf[kt][3]);
                psum += (p0 + p1) + (p2 + p3);
                uint2 w; w.x = pack2(p0, p1); w.y = pack2(p2, p3);
                *(uint2*)&Ps[wv][qt * 16 + c][kt * 16 + 4 * hg] = w;
            }
            lrun[qt] += psum;
        }

        bf16x8 vf[2][2];
#pragma unroll
        for (int dt = 0; dt < 2; ++dt)
#pragma unroll
            for (int kh = 0; kh < 2; ++kh)
                vf[dt][kh] = as_bf16x8(*(const uint4*)&Vs[cur][dt * 16 + c][kh * 32 + hg * 8]);

        __builtin_amdgcn_s_setprio(1);
#pragma unroll
        for (int qt = 0; qt < 2; ++qt)
#pragma unroll
            for (int kh = 0; kh < 2; ++kh) {
                bf16x8 pa = as_bf16x8(*(const uint4*)&Ps[wv][qt * 16 + c][kh * 32 + hg * 8]);
#pragma unroll
                for (int dt = 0; dt < 2; ++dt)
                    O[qt][dt] = __builtin_amdgcn_mfma_f32_16x16x32_bf16(
                        pa, vf[dt][kh], O[qt][dt], 0, 0, 0);
            }
        __builtin_amdgcn_s_setprio(0);

        if (haveNext) {
            *(uint4*)&Ks[cur ^ 1][k_row][k_col] = kr;
            *(uint4*)&Vs[cur ^ 1][v_d][v_kq] = vr;
            __syncthreads();
        }
    }

#pragma unroll
    for (int qt = 0; qt < 2; ++qt) {
        float Ls = lrun[qt];
        Ls += __shfl_xor(Ls, 16);
        Ls += __shfl_xor(Ls, 32);
#pragma unroll
        for (int r = 0; r < 4; ++r) {
            float lr_ = __shfl(Ls, 4 * hg + r);
            int row = q0 + qt * 16 + 4 * hg + r;
            float inv = (lr_ > 0.f) ? 1.0f / lr_ : 0.f;
            if (row < NN1) {
#pragma unroll
                for (int dt = 0; dt < 2; ++dt)
                    ao[((size_t)(b * NN1 + row)) * NC + hh * NHD + dt * 16 + c]
                        = (__bf16)(O[qt][dt][r] * inv);
            }
        }
    }
}

// ---------------------------------------------------------------------------
// Kernel 3: LePE depthwise 5x5 conv, float4 channels, 2 rows per thread,
// added into bf16 ao.
// ---------------------------------------------------------------------------
__global__ __launch_bounds__(256) void lepe2_k(
    const float* __restrict__ x, const float* __restrict__ wT,
    const float* __restrict__ bias, __bf16* __restrict__ ao)
{
    int idx = blockIdx.x * 256 + threadIdx.x;
    if (idx >= NB * (NHH / 2) * NWW * (NC / 4)) return;
    int cg = idx % (NC / 4);
    int c4 = cg * 4;
    int pos = idx / (NC / 4);
    int ww = pos % NWW;
    int hp = (pos / NWW) % (NHH / 2);
    int b = pos / (NWW * (NHH / 2));
    int hh = hp * 2;

    float4 bv = *(const float4*)(bias + c4);
    float a0[2], a1[2], a2[2], a3[2];
    a0[0] = bv.x; a1[0] = bv.y; a2[0] = bv.z; a3[0] = bv.w;
    a0[1] = bv.x; a1[1] = bv.y; a2[1] = bv.z; a3[1] = bv.w;

#pragma unroll
    for (int i = 0; i < 6; ++i) {
        int y = hh + i - 2;
        bool yv = (unsigned)y < NHH;
#pragma unroll
        for (int j = 0; j < 5; ++j) {
            int xw = ww + j - 2;
            if (yv && (unsigned)xw < NWW) {
                float4 xv = *(const float4*)(x + (((size_t)b * NHH + y) * NWW + xw) * NC + c4);
                if (i < 5) {
                    float4 wv = *(const float4*)(wT + (i * 5 + j) * NC + c4);
                    a0[0] += xv.x * wv.x; a1[0] += xv.y * wv.y;
                    a2[0] += xv.z * wv.z; a3[0] += xv.w * wv.w;
                }
                if (i >= 1) {
                    float4 wv = *(const float4*)(wT + ((i - 1) * 5 + j) * NC + c4);
                    a0[1] += xv.x * wv.x; a1[1] += xv.y * wv.y;
                    a2[1] += xv.z * wv.z; a3[1] += xv.w * wv.w;
                }
            }
        }
    }

#pragma unroll
    for (int rr = 0; rr < 2; ++rr) {
        size_t m = (size_t)b * NN1 + 1 + (hh + rr) * NWW + ww;
        uint2* aop = (uint2*)(ao + m * NC + c4);
        uint2 old = *aop;
        float r0 = a0[rr] + bf2f((unsigned short)(old.x & 0xffff));
        float r1 = a1[rr] + bf2f((unsigned short)(old.x >> 16));
        float r2 = a2[rr] + bf2f((unsigned short)(old.y & 0xffff));
        float r3 = a3[rr] + bf2f((unsigned short)(old.y >> 16));
        uint2 nw; nw.x = pack2(r0, r1); nw.y = pack2(r2, r3);
        *aop = nw;
    }
}

// ---------------------------------------------------------------------------
extern "C" void kernel_launch(void* const* d_in, const int* in_sizes, int n_in,
                              void* d_out, int out_size, void* d_ws, size_t ws_size,
                              hipStream_t stream)
{
    const float* x      = (const float*)d_in[0];
    const float* cls    = (const float*)d_in[1];
    const float* qkv_w  = (const float*)d_in[2];
    const float* proj_w = (const float*)d_in[3];
    const float* proj_b = (const float*)d_in[4];
    const float* lepe_w = (const float*)d_in[5];
    const float* lepe_b = (const float*)d_in[6];
    float* out = (float*)d_out;
    char*  ws  = (char*)d_ws;

    const size_t SEGQ = (size_t)NB * NHEAD * NN1 * NHD;     // 3,148,800
    const size_t SEGV = (size_t)NB * NHEAD * NHD * VSTRIDE; // 3,342,336
    size_t off = 0;
    __bf16* Ab    = (__bf16*)(ws + off); off += (size_t)MPAD * NC * 2;
    __bf16* wqb   = (__bf16*)(ws + off); off += (size_t)1152 * NC * 2;
    __bf16* wpb   = (__bf16*)(ws + off); off += (size_t)NC * NC * 2;
    float*  lepeT = (float*) (ws + off); off += (size_t)25 * NC * 4;
    __bf16* qg    = (__bf16*)(ws + off); off += SEGQ * 2;
    __bf16* kg    = (__bf16*)(ws + off); off += SEGQ * 2;
    __bf16* vT    = (__bf16*)(ws + off); off += SEGV * 2;
    __bf16* aob   = (__bf16*)(ws + off); off += (size_t)MPAD * NC * 2;

    {   // prep: conversions + padding
        prep_k<<<(P_TOT + 255) / 256, 256, 0, stream>>>(
            x, cls, qkv_w, proj_w, lepe_w, Ab, wqb, wpb, lepeT, aob);
    }
    {   // QKV GEMM (MFMA): 9 n-tiles x 130 m-tiles = 1170 blocks
        qkv_mfma_k<<<9 * 130, 256, 0, stream>>>(Ab, wqb, qg, kg, vT);
    }
    {   // MFMA flash attention: 864 blocks, XCD-swizzled
        attn_mfma_k<<<9 * NB * NHEAD, 256, 0, stream>>>(qg, kg, vT, aob);
    }
    {   // LePE conv added into bf16 ao (2 rows/thread)
        int total = NB * (NHW / 2) * (NC / 4);
        lepe2_k<<<(total + 255) / 256, 256, 0, stream>>>(x, lepeT, lepe_b, aob);
    }
    {   // projection GEMM (MFMA): 6 n-tiles x 65 m-tiles, 128x64
        proj_mfma_k<<<6 * 65, 256, 0, stream>>>(aob, wpb, proj_b, out);
    }
}

// Round 11
// 165.408 us; speedup vs baseline: 1.0220x; 1.0220x over previous
//
#include <hip/hip_runtime.h>
#include <math.h>

#define NB 8
#define NHH 32
#define NWW 32
#define NC 384
#define NHEAD 12
#define NHD 32
#define NN1 1025
#define NHW 1024
#define NMROWS (NB * NN1)   /* 8200 */
#define MPAD 8320           /* padded M for ao/proj (1025-based) */
#define NPB 1088            /* padded rows per batch (17*64) */
#define MP2 (NB * NPB)      /* 8704 padded global rows */
#define NMT (MP2 / 64)      /* 136 m-tiles */
#define QKT 1114112         /* per-tile elems in QKblk: 8704*128 */

typedef float f32x4 __attribute__((ext_vector_type(4)));
typedef __bf16 bf16x8 __attribute__((ext_vector_type(8)));

static __device__ __forceinline__ bf16x8 as_bf16x8(uint4 u) {
    union { uint4 a; bf16x8 b; } x; x.a = u; return x.b;
}
static __device__ __forceinline__ unsigned short bfbits(__bf16 b) {
    union { __bf16 a; unsigned short s; } u; u.a = b; return u.s;
}
static __device__ __forceinline__ float bf2f(unsigned short s) {
    union { unsigned u; float f; } x; x.u = ((unsigned)s) << 16; return x.f;
}
static __device__ __forceinline__ unsigned pack2(float a, float b) {
    return (unsigned)bfbits((__bf16)a) | ((unsigned)bfbits((__bf16)b) << 16);
}
// bijective XCD swizzle (m204)
static __device__ __forceinline__ int xcd_swz(int i, int nwg) {
    int xcd = i & 7, pos = i >> 3;
    int q = nwg >> 3, r = nwg & 7;
    return xcd * q + (xcd < r ? xcd : r) + pos;
}

// ---------------------------------------------------------------------------
// Kernel 0: prep — A=concat(cls,x) -> bf16 [8704][384] (zero pad rows),
// weights -> bf16, lepe_w transpose, zero ao pad rows.
// ---------------------------------------------------------------------------
#define P_N1 835584   /* A convert, 4-wide: 8704*384/4 */
#define P_N2 110592
#define P_N3 36864
#define P_N4 9600
#define P_N5 11520
#define P_TOT (P_N1 + P_N2 + P_N3 + P_N4 + P_N5)

__global__ __launch_bounds__(256) void prep_k(
    const float* __restrict__ x, const float* __restrict__ cls,
    const float* __restrict__ qkv_w, const float* __restrict__ proj_w,
    const float* __restrict__ lepe_w,
    __bf16* __restrict__ Ab, __bf16* __restrict__ wqb, __bf16* __restrict__ wpb,
    float* __restrict__ lepeT, __bf16* __restrict__ aob)
{
    int idx = blockIdx.x * 256 + threadIdx.x;
    if (idx >= P_TOT) return;
    if (idx < P_N1) {
        int e0 = idx * 4;
        int mp = e0 / NC, kk = e0 % NC;   // mp: padded row 0..8703
        int b = mp / NPB, n = mp % NPB;
        float4 v = make_float4(0.f, 0.f, 0.f, 0.f);
        if (n < NN1) {
            const float* src = (n == 0) ? (cls + (size_t)b * NC + kk)
                                        : (x + ((size_t)(b * NHW + (n - 1))) * NC + kk);
            v = *(const float4*)src;
        }
        uint2 u; u.x = pack2(v.x, v.y); u.y = pack2(v.z, v.w);
        *(uint2*)(Ab + (size_t)mp * NC + kk) = u;
        return;
    }
    idx -= P_N1;
    if (idx < P_N2) {
        int e0 = idx * 4;
        float4 v = *(const float4*)(qkv_w + e0);
        uint2 u; u.x = pack2(v.x, v.y); u.y = pack2(v.z, v.w);
        *(uint2*)(wqb + e0) = u;
        return;
    }
    idx -= P_N2;
    if (idx < P_N3) {
        int e0 = idx * 4;
        float4 v = *(const float4*)(proj_w + e0);
        uint2 u; u.x = pack2(v.x, v.y); u.y = pack2(v.z, v.w);
        *(uint2*)(wpb + e0) = u;
        return;
    }
    idx -= P_N3;
    if (idx < P_N4) {
        int tap = idx / NC, cc = idx % NC;
        lepeT[tap * NC + cc] = lepe_w[cc * 25 + tap];
        return;
    }
    idx -= P_N4;
    {   // zero ao pad rows 8200..8319
        uint2 z; z.x = 0; z.y = 0;
        *(uint2*)(aob + (size_t)NMROWS * NC + idx * 4) = z;
    }
}

#define LP 72
#define QSCALE 0.25505654007f   /* 1/sqrt(32) * log2(e) */
#define CPD 136

// ---------------------------------------------------------------------------
// QKV GEMM: 64x128 tile, BK=64, 4 waves (2x2 of 32x64).  Grid 136x9 = 1224.
// Outputs: q/k as [tile][m'][128] (contiguous aligned 16KB block stores),
// v as vT[h*32+d][m'] (128B-aligned spans).  Zero partial lines anywhere.
// ---------------------------------------------------------------------------
union QkvSm {
    struct { __bf16 As[64][LP]; __bf16 Bs[128][LP]; } g;
    __bf16 C[64][CPD];
};

__global__ __launch_bounds__(256) void qkv_mfma_k(
    const __bf16* __restrict__ A, const __bf16* __restrict__ W,
    __bf16* __restrict__ QKblk, __bf16* __restrict__ vT)
{
    __shared__ QkvSm sm;
    const int tid  = threadIdx.x;
    const int lane = tid & 63;
    const int wid  = tid >> 6;
    const int wr   = wid >> 1, wc = wid & 1;
    const int c    = lane & 15, hg = lane >> 4;
    const int wg   = xcd_swz(blockIdx.x, 9 * NMT);
    const int tile = wg % 9;            // 0-2: q, 3-5: k, 6-8: v
    const int m0   = (wg / 9) * 64;     // padded row base
    const int n0   = tile * 128;

    const int arow = tid >> 2, acol = (tid & 3) * 16;
    const int brow = tid >> 1, bcol = (tid & 1) * 32;

    f32x4 acc[2][4];
#pragma unroll
    for (int i = 0; i < 2; ++i)
#pragma unroll
        for (int j = 0; j < 4; ++j) acc[i][j] = f32x4{0.f, 0.f, 0.f, 0.f};

    uint4 a4[2], b4[4];
#pragma unroll
    for (int s = 0; s < 2; ++s)
        a4[s] = *(const uint4*)(A + (size_t)(m0 + arow) * NC + acol + s * 8);
#pragma unroll
    for (int s = 0; s < 4; ++s)
        b4[s] = *(const uint4*)(W + (size_t)(n0 + brow) * NC + bcol + s * 8);

    for (int k0 = 0; k0 < NC; k0 += 64) {
        __syncthreads();
#pragma unroll
        for (int s = 0; s < 2; ++s) *(uint4*)&sm.g.As[arow][acol + s * 8] = a4[s];
#pragma unroll
        for (int s = 0; s < 4; ++s) *(uint4*)&sm.g.Bs[brow][bcol + s * 8] = b4[s];
        __syncthreads();
        if (k0 + 64 < NC) {
#pragma unroll
            for (int s = 0; s < 2; ++s)
                a4[s] = *(const uint4*)(A + (size_t)(m0 + arow) * NC + k0 + 64 + acol + s * 8);
#pragma unroll
            for (int s = 0; s < 4; ++s)
                b4[s] = *(const uint4*)(W + (size_t)(n0 + brow) * NC + k0 + 64 + bcol + s * 8);
        }
#pragma unroll
        for (int ks = 0; ks < 2; ++ks) {
            bf16x8 af[2], bfr[4];
#pragma unroll
            for (int i = 0; i < 2; ++i)
                af[i] = as_bf16x8(*(const uint4*)&sm.g.As[wr * 32 + i * 16 + c][ks * 32 + hg * 8]);
#pragma unroll
            for (int j = 0; j < 4; ++j)
                bfr[j] = as_bf16x8(*(const uint4*)&sm.g.Bs[wc * 64 + j * 16 + c][ks * 32 + hg * 8]);
#pragma unroll
            for (int i = 0; i < 2; ++i)
#pragma unroll
                for (int j = 0; j < 4; ++j)
                    acc[i][j] = __builtin_amdgcn_mfma_f32_16x16x32_bf16(
                        af[i], bfr[j], acc[i][j], 0, 0, 0);
        }
    }

    __syncthreads();   // reuse LDS as C staging
    const float qs = (tile < 3) ? QSCALE : 1.0f;
#pragma unroll
    for (int i = 0; i < 2; ++i)
#pragma unroll
        for (int r = 0; r < 4; ++r) {
            int row = wr * 32 + i * 16 + 4 * hg + r;
#pragma unroll
            for (int j = 0; j < 4; ++j)
                sm.C[row][wc * 64 + j * 16 + c] = (__bf16)(acc[i][j][r] * qs);
        }
    __syncthreads();

    if (tile < 6) {
        // q/k: one contiguous 16KB aligned span per block
        __bf16* dst = QKblk + (size_t)tile * QKT + (size_t)m0 * 128;
#pragma unroll
        for (int it = 0; it < 4; ++it) {
            int idx  = it * 256 + tid;        // 0..1023 uint4s
            int r    = idx >> 4;              // 0..63
            int col0 = (idx & 15) * 8;
            uint4 u = *(const uint4*)&sm.C[r][col0];
            *(uint4*)(dst + (size_t)idx * 8) = u;
        }
    } else {
        // v: vT[(tseg*4+hl)*32+d][m0..m0+63], 128B-aligned spans
        const int tseg = tile - 6;
        const unsigned short* CS = (const unsigned short*)&sm.C[0][0];
#pragma unroll
        for (int it = 0; it < 4; ++it) {
            int idx     = it * 256 + tid;     // 0..1023
            int row_out = idx & 127;          // hl*32 + d
            int span    = idx >> 7;           // 0..7
            int vrow    = (tseg * 4 + (row_out >> 5)) * 32 + (row_out & 31);
            unsigned short e[8];
#pragma unroll
            for (int u = 0; u < 8; ++u)
                e[u] = CS[(span * 8 + u) * CPD + row_out];
            uint4 o;
            o.x = (unsigned)e[0] | ((unsigned)e[1] << 16);
            o.y = (unsigned)e[2] | ((unsigned)e[3] << 16);
            o.z = (unsigned)e[4] | ((unsigned)e[5] << 16);
            o.w = (unsigned)e[6] | ((unsigned)e[7] << 16);
            *(uint4*)(vT + (size_t)vrow * MP2 + m0 + span * 8) = o;
        }
    }
}

// ---------------------------------------------------------------------------
// proj GEMM: 128x64 tile, register-prefetched K-loop (unchanged).
// ---------------------------------------------------------------------------
__global__ __launch_bounds__(256) void proj_mfma_k(
    const __bf16* __restrict__ A, const __bf16* __restrict__ W,
    const float* __restrict__ bias, float* __restrict__ out)
{
    __shared__ __bf16 As[128][LP];
    __shared__ __bf16 Bs[64][LP];
    const int tid  = threadIdx.x;
    const int lane = tid & 63;
    const int wid  = tid >> 6;
    const int wr   = wid >> 1, wc = wid & 1;
    const int c    = lane & 15, hg = lane >> 4;
    const int wg   = xcd_swz(blockIdx.x, 6 * 65);
    const int m0   = (wg / 6) * 128;
    const int n0   = (wg % 6) * 64;
    const int srow = tid >> 1;
    const int scol = (tid & 1) * 32;
    const int brow = tid >> 2;
    const int bcol = (tid & 3) * 16;

    f32x4 acc[4][2];
#pragma unroll
    for (int i = 0; i < 4; ++i)
#pragma unroll
        for (int j = 0; j < 2; ++j) acc[i][j] = f32x4{0.f, 0.f, 0.f, 0.f};

    uint4 a4[4], b4[2];
#pragma unroll
    for (int s = 0; s < 4; ++s)
        a4[s] = *(const uint4*)(A + (size_t)(m0 + srow) * NC + scol + s * 8);
#pragma unroll
    for (int s = 0; s < 2; ++s)
        b4[s] = *(const uint4*)(W + (size_t)(n0 + brow) * NC + bcol + s * 8);

    for (int k0 = 0; k0 < NC; k0 += 64) {
        __syncthreads();
#pragma unroll
        for (int s = 0; s < 4; ++s) *(uint4*)&As[srow][scol + s * 8] = a4[s];
#pragma unroll
        for (int s = 0; s < 2; ++s) *(uint4*)&Bs[brow][bcol + s * 8] = b4[s];
        __syncthreads();
        if (k0 + 64 < NC) {
#pragma unroll
            for (int s = 0; s < 4; ++s)
                a4[s] = *(const uint4*)(A + (size_t)(m0 + srow) * NC + k0 + 64 + scol + s * 8);
#pragma unroll
            for (int s = 0; s < 2; ++s)
                b4[s] = *(const uint4*)(W + (size_t)(n0 + brow) * NC + k0 + 64 + bcol + s * 8);
        }
#pragma unroll
        for (int ks = 0; ks < 2; ++ks) {
            bf16x8 af[4], bfr[2];
#pragma unroll
            for (int i = 0; i < 4; ++i)
                af[i] = as_bf16x8(*(const uint4*)&As[wr * 64 + i * 16 + c][ks * 32 + hg * 8]);
#pragma unroll
            for (int j = 0; j < 2; ++j)
                bfr[j] = as_bf16x8(*(const uint4*)&Bs[wc * 32 + j * 16 + c][ks * 32 + hg * 8]);
#pragma unroll
            for (int i = 0; i < 4; ++i)
#pragma unroll
                for (int j = 0; j < 2; ++j)
                    acc[i][j] = __builtin_amdgcn_mfma_f32_16x16x32_bf16(
                        af[i], bfr[j], acc[i][j], 0, 0, 0);
        }
    }

#pragma unroll
    for (int i = 0; i < 4; ++i)
#pragma unroll
        for (int r = 0; r < 4; ++r) {
            int m = m0 + wr * 64 + i * 16 + 4 * hg + r;
            if (m >= NMROWS) continue;
            int b = m / NN1, n = m % NN1;
            float* dstrow = (n == 0)
                ? (out + (size_t)NB * NHW * NC + (size_t)b * NC)
                : (out + ((size_t)(b * NHW) + (n - 1)) * NC);
#pragma unroll
            for (int j = 0; j < 2; ++j) {
                int col = n0 + wc * 32 + j * 16 + c;
                dstrow[col] = acc[i][j][r] + bias[col];
            }
        }
}

// ---------------------------------------------------------------------------
// Kernel 2: bf16-MFMA flash attention.  Blocked q/k reads ([tile][m'][128]),
// vT[d-row][m'] reads; all address math is shifts, all loads 16B-aligned.
// ---------------------------------------------------------------------------
#define KC 64
#define KPAD 40
#define VPAD 72
#define PPAD 72
#define NCH ((NN1 + KC - 1) / KC)   /* 17; chunk keys reach 1087 < NPB */

__global__ __launch_bounds__(256) void attn_mfma_k(
    const __bf16* __restrict__ QKblk, const __bf16* __restrict__ vT,
    __bf16* __restrict__ ao)
{
    __shared__ unsigned short Ks[2][KC][KPAD];
    __shared__ unsigned short Vs[2][32][VPAD];
    __shared__ unsigned short Ps[4][32][PPAD];

    const int wg    = xcd_swz(blockIdx.x, 9 * NB * NHEAD);
    const int qtile = wg % 9;
    const int bh    = wg / 9;
    const int b     = bh / NHEAD;
    const int hh    = bh % NHEAD;
    const int tid   = threadIdx.x;
    const int wv    = tid >> 6;
    const int lane  = tid & 63;
    const int c     = lane & 15;
    const int hg    = lane >> 4;
    const int q0    = qtile * 128 + wv * 32;
    const size_t MBp = (size_t)b * NPB;

    const __bf16* qb = QKblk + (size_t)(hh >> 2) * QKT + (hh & 3) * 32;
    const __bf16* kb = QKblk + (size_t)(3 + (hh >> 2)) * QKT + (hh & 3) * 32;

    uint4 zero4 = make_uint4(0, 0, 0, 0);
    bf16x8 qf[2];
#pragma unroll
    for (int qt = 0; qt < 2; ++qt) {
        int row = q0 + qt * 16 + c;
        uint4 u = (row < NN1)
            ? *(const uint4*)(qb + (MBp + row) * 128 + hg * 8) : zero4;
        qf[qt] = as_bf16x8(u);
    }

    f32x4 O[2][2];
#pragma unroll
    for (int qt = 0; qt < 2; ++qt)
#pragma unroll
        for (int dt = 0; dt < 2; ++dt) O[qt][dt] = f32x4{0.f, 0.f, 0.f, 0.f};
    float lrun[2] = {0.f, 0.f};

    const int k_row = tid >> 2;          // key 0..63
    const int k_col = (tid & 3) * 8;
    const int v_d   = tid >> 3;          // 0..31
    const int v_kq  = (tid & 7) * 8;
    const __bf16* vrow_p = vT + (size_t)(hh * NHD + v_d) * MP2 + MBp;

    uint4 kr = *(const uint4*)(kb + (MBp + k_row) * 128 + k_col);
    uint4 vr = *(const uint4*)(vrow_p + v_kq);
    *(uint4*)&Ks[0][k_row][k_col] = kr;
    *(uint4*)&Vs[0][v_d][v_kq] = vr;
    __syncthreads();

    for (int t = 0; t < NCH; ++t) {
        const int kt0 = t * KC;
        const int cur = t & 1;
        const bool haveNext = (t + 1 < NCH);
        if (haveNext) {   // pad keys exist up to 1087: no guard needed
            kr = *(const uint4*)(kb + (MBp + kt0 + KC + k_row) * 128 + k_col);
            vr = *(const uint4*)(vrow_p + kt0 + KC + v_kq);
        }
        const bool full = (kt0 + KC <= NN1);

        bf16x8 kf[4];
#pragma unroll
        for (int kt = 0; kt < 4; ++kt)
            kf[kt] = as_bf16x8(*(const uint4*)&Ks[cur][kt * 16 + c][hg * 8]);

#pragma unroll
        for (int qt = 0; qt < 2; ++qt) {
            f32x4 Sf[4];
            __builtin_amdgcn_s_setprio(1);
#pragma unroll
            for (int kt = 0; kt < 4; ++kt)
                Sf[kt] = __builtin_amdgcn_mfma_f32_16x16x32_bf16(
                    kf[kt], qf[qt], f32x4{0.f, 0.f, 0.f, 0.f}, 0, 0, 0);
            __builtin_amdgcn_s_setprio(0);

            if (!full) {   // mask pad keys (exp2(-3e38)==0)
#pragma unroll
                for (int kt = 0; kt < 4; ++kt)
#pragma unroll
                    for (int r = 0; r < 4; ++r) {
                        int key = kt0 + kt * 16 + 4 * hg + r;
                        if (key >= NN1) Sf[kt][r] = -3.0e38f;
                    }
            }
            float psum = 0.f;
#pragma unroll
            for (int kt = 0; kt < 4; ++kt) {
                float p0 = exp2f(Sf[kt][0]);
                float p1 = exp2f(Sf[kt][1]);
                float p2 = exp2f(Sf[kt][2]);
                float p3 = exp2f(Sf[kt][3]);
                psum += (p0 + p1) + (p2 + p3);
                uint2 w; w.x = pack2(p0, p1); w.y = pack2(p2, p3);
                *(uint2*)&Ps[wv][qt * 16 + c][kt * 16 + 4 * hg] = w;
            }
            lrun[qt] += psum;
        }

        bf16x8 vf[2][2];
#pragma unroll
        for (int dt = 0; dt < 2; ++dt)
#pragma unroll
            for (int kh = 0; kh < 2; ++kh)
                vf[dt][kh] = as_bf16x8(*(const uint4*)&Vs[cur][dt * 16 + c][kh * 32 + hg * 8]);

        __builtin_amdgcn_s_setprio(1);
#pragma unroll
        for (int qt = 0; qt < 2; ++qt)
#pragma unroll
            for (int kh = 0; kh < 2; ++kh) {
                bf16x8 pa = as_bf16x8(*(const uint4*)&Ps[wv][qt * 16 + c][kh * 32 + hg * 8]);
#pragma unroll
                for (int dt = 0; dt < 2; ++dt)
                    O[qt][dt] = __builtin_amdgcn_mfma_f32_16x16x32_bf16(
                        pa, vf[dt][kh], O[qt][dt], 0, 0, 0);
            }
        __builtin_amdgcn_s_setprio(0);

        if (haveNext) {
            *(uint4*)&Ks[cur ^ 1][k_row][k_col] = kr;
            *(uint4*)&Vs[cur ^ 1][v_d][v_kq] = vr;
            __syncthreads();
        }
    }

#pragma unroll
    for (int qt = 0; qt < 2; ++qt) {
        float Ls = lrun[qt];
        Ls += __shfl_xor(Ls, 16);
        Ls += __shfl_xor(Ls, 32);
#pragma unroll
        for (int r = 0; r < 4; ++r) {
            float lr_ = __shfl(Ls, 4 * hg + r);
            int row = q0 + qt * 16 + 4 * hg + r;
            float inv = (lr_ > 0.f) ? 1.0f / lr_ : 0.f;
            if (row < NN1) {
#pragma unroll
                for (int dt = 0; dt < 2; ++dt)
                    ao[((size_t)(b * NN1 + row)) * NC + hh * NHD + dt * 16 + c]
                        = (__bf16)(O[qt][dt][r] * inv);
            }
        }
    }
}

// ---------------------------------------------------------------------------
// Kernel 3: LePE depthwise 5x5 conv, 2 rows/thread, added into bf16 ao.
// ---------------------------------------------------------------------------
__global__ __launch_bounds__(256) void lepe2_k(
    const float* __restrict__ x, const float* __restrict__ wT,
    const float* __restrict__ bias, __bf16* __restrict__ ao)
{
    int idx = blockIdx.x * 256 + threadIdx.x;
    if (idx >= NB * (NHH / 2) * NWW * (NC / 4)) return;
    int cg = idx % (NC / 4);
    int c4 = cg * 4;
    int pos = idx / (NC / 4);
    int ww = pos % NWW;
    int hp = (pos / NWW) % (NHH / 2);
    int b = pos / (NWW * (NHH / 2));
    int hh = hp * 2;

    float4 bv = *(const float4*)(bias + c4);
    float a0[2], a1[2], a2[2], a3[2];
    a0[0] = bv.x; a1[0] = bv.y; a2[0] = bv.z; a3[0] = bv.w;
    a0[1] = bv.x; a1[1] = bv.y; a2[1] = bv.z; a3[1] = bv.w;

#pragma unroll
    for (int i = 0; i < 6; ++i) {
        int y = hh + i - 2;
        bool yv = (unsigned)y < NHH;
#pragma unroll
        for (int j = 0; j < 5; ++j) {
            int xw = ww + j - 2;
            if (yv && (unsigned)xw < NWW) {
                float4 xv = *(const float4*)(x + (((size_t)b * NHH + y) * NWW + xw) * NC + c4);
                if (i < 5) {
                    float4 wv = *(const float4*)(wT + (i * 5 + j) * NC + c4);
                    a0[0] += xv.x * wv.x; a1[0] += xv.y * wv.y;
                    a2[0] += xv.z * wv.z; a3[0] += xv.w * wv.w;
                }
                if (i >= 1) {
                    float4 wv = *(const float4*)(wT + ((i - 1) * 5 + j) * NC + c4);
                    a0[1] += xv.x * wv.x; a1[1] += xv.y * wv.y;
                    a2[1] += xv.z * wv.z; a3[1] += xv.w * wv.w;
                }
            }
        }
    }

#pragma unroll
    for (int rr = 0; rr < 2; ++rr) {
        size_t m = (size_t)b * NN1 + 1 + (hh + rr) * NWW + ww;
        uint2* aop = (uint2*)(ao + m * NC + c4);
        uint2 old = *aop;
        float r0 = a0[rr] + bf2f((unsigned short)(old.x & 0xffff));
        float r1 = a1[rr] + bf2f((unsigned short)(old.x >> 16));
        float r2 = a2[rr] + bf2f((unsigned short)(old.y & 0xffff));
        float r3 = a3[rr] + bf2f((unsigned short)(old.y >> 16));
        uint2 nw; nw.x = pack2(r0, r1); nw.y = pack2(r2, r3);
        *aop = nw;
    }
}

// ---------------------------------------------------------------------------
extern "C" void kernel_launch(void* const* d_in, const int* in_sizes, int n_in,
                              void* d_out, int out_size, void* d_ws, size_t ws_size,
                              hipStream_t stream)
{
    const float* x      = (const float*)d_in[0];
    const float* cls    = (const float*)d_in[1];
    const float* qkv_w  = (const float*)d_in[2];
    const float* proj_w = (const float*)d_in[3];
    const float* proj_b = (const float*)d_in[4];
    const float* lepe_w = (const float*)d_in[5];
    const float* lepe_b = (const float*)d_in[6];
    float* out = (float*)d_out;
    char*  ws  = (char*)d_ws;

    size_t off = 0;
    __bf16* Ab    = (__bf16*)(ws + off); off += (size_t)MP2 * NC * 2;        // 6.68MB
    __bf16* wqb   = (__bf16*)(ws + off); off += (size_t)1152 * NC * 2;       // 0.88MB
    __bf16* wpb   = (__bf16*)(ws + off); off += (size_t)NC * NC * 2;         // 0.29MB
    float*  lepeT = (float*) (ws + off); off += (size_t)25 * NC * 4;         // 38KB
    __bf16* QKblk = (__bf16*)(ws + off); off += (size_t)6 * QKT * 2;         // 13.37MB
    __bf16* vT    = (__bf16*)(ws + off); off += (size_t)NC * MP2 * 2;        // 6.68MB
    __bf16* aob   = (__bf16*)(ws + off); off += (size_t)MPAD * NC * 2;       // 6.39MB

    {   // prep
        prep_k<<<(P_TOT + 255) / 256, 256, 0, stream>>>(
            x, cls, qkv_w, proj_w, lepe_w, Ab, wqb, wpb, lepeT, aob);
    }
    {   // QKV GEMM: 9 tiles x 136 m-tiles = 1224 blocks
        qkv_mfma_k<<<9 * NMT, 256, 0, stream>>>(Ab, wqb, QKblk, vT);
    }
    {   // flash attention: 864 blocks
        attn_mfma_k<<<9 * NB * NHEAD, 256, 0, stream>>>(QKblk, vT, aob);
    }
    {   // LePE conv
        int total = NB * (NHW / 2) * (NC / 4);
        lepe2_k<<<(total + 255) / 256, 256, 0, stream>>>(x, lepeT, lepe_b, aob);
    }
    {   // projection GEMM
        proj_mfma_k<<<6 * 65, 256, 0, stream>>>(aob, wpb, proj_b, out);
    }
}

// Round 12
// 165.234 us; speedup vs baseline: 1.0231x; 1.0011x over previous
//
#include <hip/hip_runtime.h>
#include <math.h>

#define NB 8
#define NHH 32
#define NWW 32
#define NC 384
#define NHEAD 12
#define NHD 32
#define NN1 1025
#define NHW 1024
#define NMROWS (NB * NN1)   /* 8200 */
#define MPAD 8320           /* padded M for ao/proj (1025-based) */
#define NPB 1088            /* padded rows per batch (17*64) */
#define MP2 (NB * NPB)      /* 8704 padded global rows */
#define NMT (MP2 / 64)      /* 136 m-tiles */
#define CST 1152            /* canonical C row stride (cols) */

typedef float f32x4 __attribute__((ext_vector_type(4)));
typedef __bf16 bf16x8 __attribute__((ext_vector_type(8)));

static __device__ __forceinline__ bf16x8 as_bf16x8(uint4 u) {
    union { uint4 a; bf16x8 b; } x; x.a = u; return x.b;
}
static __device__ __forceinline__ unsigned short bfbits(__bf16 b) {
    union { __bf16 a; unsigned short s; } u; u.a = b; return u.s;
}
static __device__ __forceinline__ float bf2f(unsigned short s) {
    union { unsigned u; float f; } x; x.u = ((unsigned)s) << 16; return x.f;
}
static __device__ __forceinline__ unsigned pack2(float a, float b) {
    return (unsigned)bfbits((__bf16)a) | ((unsigned)bfbits((__bf16)b) << 16);
}
// bijective XCD swizzle (m204)
static __device__ __forceinline__ int xcd_swz(int i, int nwg) {
    int xcd = i & 7, pos = i >> 3;
    int q = nwg >> 3, r = nwg & 7;
    return xcd * q + (xcd < r ? xcd : r) + pos;
}

// ---------------------------------------------------------------------------
// Kernel 0: prep — A=concat(cls,x) -> bf16 [8704][384] (zero pad rows),
// weights -> bf16, lepe_w transpose, zero ao pad rows.
// ---------------------------------------------------------------------------
#define P_N1 835584   /* A convert, 4-wide: 8704*384/4 */
#define P_N2 110592
#define P_N3 36864
#define P_N4 9600
#define P_N5 11520
#define P_TOT (P_N1 + P_N2 + P_N3 + P_N4 + P_N5)

__global__ __launch_bounds__(256) void prep_k(
    const float* __restrict__ x, const float* __restrict__ cls,
    const float* __restrict__ qkv_w, const float* __restrict__ proj_w,
    const float* __restrict__ lepe_w,
    __bf16* __restrict__ Ab, __bf16* __restrict__ wqb, __bf16* __restrict__ wpb,
    float* __restrict__ lepeT, __bf16* __restrict__ aob)
{
    int idx = blockIdx.x * 256 + threadIdx.x;
    if (idx >= P_TOT) return;
    if (idx < P_N1) {
        int e0 = idx * 4;
        int mp = e0 / NC, kk = e0 % NC;
        int b = mp / NPB, n = mp % NPB;
        float4 v = make_float4(0.f, 0.f, 0.f, 0.f);
        if (n < NN1) {
            const float* src = (n == 0) ? (cls + (size_t)b * NC + kk)
                                        : (x + ((size_t)(b * NHW + (n - 1))) * NC + kk);
            v = *(const float4*)src;
        }
        uint2 u; u.x = pack2(v.x, v.y); u.y = pack2(v.z, v.w);
        *(uint2*)(Ab + (size_t)mp * NC + kk) = u;
        return;
    }
    idx -= P_N1;
    if (idx < P_N2) {
        int e0 = idx * 4;
        float4 v = *(const float4*)(qkv_w + e0);
        uint2 u; u.x = pack2(v.x, v.y); u.y = pack2(v.z, v.w);
        *(uint2*)(wqb + e0) = u;
        return;
    }
    idx -= P_N2;
    if (idx < P_N3) {
        int e0 = idx * 4;
        float4 v = *(const float4*)(proj_w + e0);
        uint2 u; u.x = pack2(v.x, v.y); u.y = pack2(v.z, v.w);
        *(uint2*)(wpb + e0) = u;
        return;
    }
    idx -= P_N3;
    if (idx < P_N4) {
        int tap = idx / NC, cc = idx % NC;
        lepeT[tap * NC + cc] = lepe_w[cc * 25 + tap];
        return;
    }
    idx -= P_N4;
    {   // zero ao pad rows 8200..8319
        uint2 z; z.x = 0; z.y = 0;
        *(uint2*)(aob + (size_t)NMROWS * NC + idx * 4) = z;
    }
}

#define LP 72
#define QSCALE 0.25505654007f   /* 1/sqrt(32) * log2(e) */
#define CPD 136

// ---------------------------------------------------------------------------
// QKV GEMM: 64x128 tile, BK=64, 4 waves (2x2 of 32x64).  Grid 136x9 = 1224.
// Output: canonical row-major C[8704][1152].  Each block writes 64 rows x
// 256B contiguous segments — single surface, full lines, no branches.
// ---------------------------------------------------------------------------
union QkvSm {
    struct { __bf16 As[64][LP]; __bf16 Bs[128][LP]; } g;
    __bf16 C[64][CPD];
};

__global__ __launch_bounds__(256) void qkv_mfma_k(
    const __bf16* __restrict__ A, const __bf16* __restrict__ W,
    __bf16* __restrict__ Cg)
{
    __shared__ QkvSm sm;
    const int tid  = threadIdx.x;
    const int lane = tid & 63;
    const int wid  = tid >> 6;
    const int wr   = wid >> 1, wc = wid & 1;
    const int c    = lane & 15, hg = lane >> 4;
    const int wg   = xcd_swz(blockIdx.x, 9 * NMT);
    const int tile = wg % 9;
    const int m0   = (wg / 9) * 64;
    const int n0   = tile * 128;

    const int arow = tid >> 2, acol = (tid & 3) * 16;
    const int brow = tid >> 1, bcol = (tid & 1) * 32;

    f32x4 acc[2][4];
#pragma unroll
    for (int i = 0; i < 2; ++i)
#pragma unroll
        for (int j = 0; j < 4; ++j) acc[i][j] = f32x4{0.f, 0.f, 0.f, 0.f};

    uint4 a4[2], b4[4];
#pragma unroll
    for (int s = 0; s < 2; ++s)
        a4[s] = *(const uint4*)(A + (size_t)(m0 + arow) * NC + acol + s * 8);
#pragma unroll
    for (int s = 0; s < 4; ++s)
        b4[s] = *(const uint4*)(W + (size_t)(n0 + brow) * NC + bcol + s * 8);

    for (int k0 = 0; k0 < NC; k0 += 64) {
        __syncthreads();
#pragma unroll
        for (int s = 0; s < 2; ++s) *(uint4*)&sm.g.As[arow][acol + s * 8] = a4[s];
#pragma unroll
        for (int s = 0; s < 4; ++s) *(uint4*)&sm.g.Bs[brow][bcol + s * 8] = b4[s];
        __syncthreads();
        if (k0 + 64 < NC) {
#pragma unroll
            for (int s = 0; s < 2; ++s)
                a4[s] = *(const uint4*)(A + (size_t)(m0 + arow) * NC + k0 + 64 + acol + s * 8);
#pragma unroll
            for (int s = 0; s < 4; ++s)
                b4[s] = *(const uint4*)(W + (size_t)(n0 + brow) * NC + k0 + 64 + bcol + s * 8);
        }
#pragma unroll
        for (int ks = 0; ks < 2; ++ks) {
            bf16x8 af[2], bfr[4];
#pragma unroll
            for (int i = 0; i < 2; ++i)
                af[i] = as_bf16x8(*(const uint4*)&sm.g.As[wr * 32 + i * 16 + c][ks * 32 + hg * 8]);
#pragma unroll
            for (int j = 0; j < 4; ++j)
                bfr[j] = as_bf16x8(*(const uint4*)&sm.g.Bs[wc * 64 + j * 16 + c][ks * 32 + hg * 8]);
#pragma unroll
            for (int i = 0; i < 2; ++i)
#pragma unroll
                for (int j = 0; j < 4; ++j)
                    acc[i][j] = __builtin_amdgcn_mfma_f32_16x16x32_bf16(
                        af[i], bfr[j], acc[i][j], 0, 0, 0);
        }
    }

    __syncthreads();   // reuse LDS as C staging
    const float qs = (tile < 3) ? QSCALE : 1.0f;
#pragma unroll
    for (int i = 0; i < 2; ++i)
#pragma unroll
        for (int r = 0; r < 4; ++r) {
            int row = wr * 32 + i * 16 + 4 * hg + r;
#pragma unroll
            for (int j = 0; j < 4; ++j)
                sm.C[row][wc * 64 + j * 16 + c] = (__bf16)(acc[i][j][r] * qs);
        }
    __syncthreads();

    // canonical write: row m0+row, cols n0..n0+127 (256B contiguous/row)
#pragma unroll
    for (int it = 0; it < 4; ++it) {
        int idx   = it * 256 + tid;      // 0..1023 uint4s
        int row   = idx >> 4;            // 0..63
        int chunk = idx & 15;            // 16B chunk within 256B row seg
        uint4 u = *(const uint4*)&sm.C[row][chunk * 8];
        *(uint4*)(Cg + (size_t)(m0 + row) * CST + n0 + chunk * 8) = u;
    }
}

// ---------------------------------------------------------------------------
// proj GEMM: 128x64 tile, register-prefetched K-loop (unchanged).
// ---------------------------------------------------------------------------
__global__ __launch_bounds__(256) void proj_mfma_k(
    const __bf16* __restrict__ A, const __bf16* __restrict__ W,
    const float* __restrict__ bias, float* __restrict__ out)
{
    __shared__ __bf16 As[128][LP];
    __shared__ __bf16 Bs[64][LP];
    const int tid  = threadIdx.x;
    const int lane = tid & 63;
    const int wid  = tid >> 6;
    const int wr   = wid >> 1, wc = wid & 1;
    const int c    = lane & 15, hg = lane >> 4;
    const int wg   = xcd_swz(blockIdx.x, 6 * 65);
    const int m0   = (wg / 6) * 128;
    const int n0   = (wg % 6) * 64;
    const int srow = tid >> 1;
    const int scol = (tid & 1) * 32;
    const int brow = tid >> 2;
    const int bcol = (tid & 3) * 16;

    f32x4 acc[4][2];
#pragma unroll
    for (int i = 0; i < 4; ++i)
#pragma unroll
        for (int j = 0; j < 2; ++j) acc[i][j] = f32x4{0.f, 0.f, 0.f, 0.f};

    uint4 a4[4], b4[2];
#pragma unroll
    for (int s = 0; s < 4; ++s)
        a4[s] = *(const uint4*)(A + (size_t)(m0 + srow) * NC + scol + s * 8);
#pragma unroll
    for (int s = 0; s < 2; ++s)
        b4[s] = *(const uint4*)(W + (size_t)(n0 + brow) * NC + bcol + s * 8);

    for (int k0 = 0; k0 < NC; k0 += 64) {
        __syncthreads();
#pragma unroll
        for (int s = 0; s < 4; ++s) *(uint4*)&As[srow][scol + s * 8] = a4[s];
#pragma unroll
        for (int s = 0; s < 2; ++s) *(uint4*)&Bs[brow][bcol + s * 8] = b4[s];
        __syncthreads();
        if (k0 + 64 < NC) {
#pragma unroll
            for (int s = 0; s < 4; ++s)
                a4[s] = *(const uint4*)(A + (size_t)(m0 + srow) * NC + k0 + 64 + scol + s * 8);
#pragma unroll
            for (int s = 0; s < 2; ++s)
                b4[s] = *(const uint4*)(W + (size_t)(n0 + brow) * NC + k0 + 64 + bcol + s * 8);
        }
#pragma unroll
        for (int ks = 0; ks < 2; ++ks) {
            bf16x8 af[4], bfr[2];
#pragma unroll
            for (int i = 0; i < 4; ++i)
                af[i] = as_bf16x8(*(const uint4*)&As[wr * 64 + i * 16 + c][ks * 32 + hg * 8]);
#pragma unroll
            for (int j = 0; j < 2; ++j)
                bfr[j] = as_bf16x8(*(const uint4*)&Bs[wc * 32 + j * 16 + c][ks * 32 + hg * 8]);
#pragma unroll
            for (int i = 0; i < 4; ++i)
#pragma unroll
                for (int j = 0; j < 2; ++j)
                    acc[i][j] = __builtin_amdgcn_mfma_f32_16x16x32_bf16(
                        af[i], bfr[j], acc[i][j], 0, 0, 0);
        }
    }

#pragma unroll
    for (int i = 0; i < 4; ++i)
#pragma unroll
        for (int r = 0; r < 4; ++r) {
            int m = m0 + wr * 64 + i * 16 + 4 * hg + r;
            if (m >= NMROWS) continue;
            int b = m / NN1, n = m % NN1;
            float* dstrow = (n == 0)
                ? (out + (size_t)NB * NHW * NC + (size_t)b * NC)
                : (out + ((size_t)(b * NHW) + (n - 1)) * NC);
#pragma unroll
            for (int j = 0; j < 2; ++j) {
                int col = n0 + wc * 32 + j * 16 + c;
                dstrow[col] = acc[i][j][r] + bias[col];
            }
        }
}

// ---------------------------------------------------------------------------
// Kernel 2: bf16-MFMA flash attention reading canonical C.
// q cols hh*32, k cols 384+hh*32, v cols 768+hh*32; row stride 1152.
// V transposed into LDS at stage time (conflicts measured immaterial R6-R9).
// ---------------------------------------------------------------------------
#define KC 64
#define KPAD 40
#define VPAD 72
#define PPAD 72
#define NCH ((NN1 + KC - 1) / KC)   /* 17; chunk keys reach 1087 < NPB */

__global__ __launch_bounds__(256) void attn_mfma_k(
    const __bf16* __restrict__ Cg, __bf16* __restrict__ ao)
{
    __shared__ unsigned short Ks[2][KC][KPAD];
    __shared__ unsigned short Vs[2][32][VPAD];
    __shared__ unsigned short Ps[4][32][PPAD];

    const int wg    = xcd_swz(blockIdx.x, 9 * NB * NHEAD);
    const int qtile = wg % 9;
    const int bh    = wg / 9;
    const int b     = bh / NHEAD;
    const int hh    = bh % NHEAD;
    const int tid   = threadIdx.x;
    const int wv    = tid >> 6;
    const int lane  = tid & 63;
    const int c     = lane & 15;
    const int hg    = lane >> 4;
    const int q0    = qtile * 128 + wv * 32;
    const size_t MBp = (size_t)b * NPB;

    const __bf16* qb = Cg + hh * 32;
    const __bf16* kb = Cg + 384 + hh * 32;
    const __bf16* vb = Cg + 768 + hh * 32;

    uint4 zero4 = make_uint4(0, 0, 0, 0);
    bf16x8 qf[2];
#pragma unroll
    for (int qt = 0; qt < 2; ++qt) {
        int row = q0 + qt * 16 + c;
        uint4 u = (row < NN1)
            ? *(const uint4*)(qb + (MBp + row) * CST + hg * 8) : zero4;
        qf[qt] = as_bf16x8(u);
    }

    f32x4 O[2][2];
#pragma unroll
    for (int qt = 0; qt < 2; ++qt)
#pragma unroll
        for (int dt = 0; dt < 2; ++dt) O[qt][dt] = f32x4{0.f, 0.f, 0.f, 0.f};
    float lrun[2] = {0.f, 0.f};

    const int k_row = tid >> 2;          // key 0..63
    const int k_col = (tid & 3) * 8;     // d0: 0,8,16,24

    // prologue: stage chunk 0 (K direct, V via LDS transpose)
    uint4 kr = *(const uint4*)(kb + (MBp + k_row) * CST + k_col);
    uint4 vr = *(const uint4*)(vb + (MBp + k_row) * CST + k_col);
    *(uint4*)&Ks[0][k_row][k_col] = kr;
    {
        union { uint4 u; unsigned short s[8]; } vu; vu.u = vr;
#pragma unroll
        for (int j = 0; j < 8; ++j) Vs[0][k_col + j][k_row] = vu.s[j];
    }
    __syncthreads();

    for (int t = 0; t < NCH; ++t) {
        const int kt0 = t * KC;
        const int cur = t & 1;
        const bool haveNext = (t + 1 < NCH);
        if (haveNext) {   // pad rows (zeros) exist to 1087: no guard needed
            kr = *(const uint4*)(kb + (MBp + kt0 + KC + k_row) * CST + k_col);
            vr = *(const uint4*)(vb + (MBp + kt0 + KC + k_row) * CST + k_col);
        }
        const bool full = (kt0 + KC <= NN1);

        bf16x8 kf[4];
#pragma unroll
        for (int kt = 0; kt < 4; ++kt)
            kf[kt] = as_bf16x8(*(const uint4*)&Ks[cur][kt * 16 + c][hg * 8]);

#pragma unroll
        for (int qt = 0; qt < 2; ++qt) {
            f32x4 Sf[4];
            __builtin_amdgcn_s_setprio(1);
#pragma unroll
            for (int kt = 0; kt < 4; ++kt)
                Sf[kt] = __builtin_amdgcn_mfma_f32_16x16x32_bf16(
                    kf[kt], qf[qt], f32x4{0.f, 0.f, 0.f, 0.f}, 0, 0, 0);
            __builtin_amdgcn_s_setprio(0);

            if (!full) {   // mask pad keys (exp2(-3e38)==0)
#pragma unroll
                for (int kt = 0; kt < 4; ++kt)
#pragma unroll
                    for (int r = 0; r < 4; ++r) {
                        int key = kt0 + kt * 16 + 4 * hg + r;
                        if (key >= NN1) Sf[kt][r] = -3.0e38f;
                    }
            }
            float psum = 0.f;
#pragma unroll
            for (int kt = 0; kt < 4; ++kt) {
                float p0 = exp2f(Sf[kt][0]);
                float p1 = exp2f(Sf[kt][1]);
                float p2 = exp2f(Sf[kt][2]);
                float p3 = exp2f(Sf[kt][3]);
                psum += (p0 + p1) + (p2 + p3);
                uint2 w; w.x = pack2(p0, p1); w.y = pack2(p2, p3);
                *(uint2*)&Ps[wv][qt * 16 + c][kt * 16 + 4 * hg] = w;
            }
            lrun[qt] += psum;
        }

        bf16x8 vf[2][2];
#pragma unroll
        for (int dt = 0; dt < 2; ++dt)
#pragma unroll
            for (int kh = 0; kh < 2; ++kh)
                vf[dt][kh] = as_bf16x8(*(const uint4*)&Vs[cur][dt * 16 + c][kh * 32 + hg * 8]);

        __builtin_amdgcn_s_setprio(1);
#pragma unroll
        for (int qt = 0; qt < 2; ++qt)
#pragma unroll
            for (int kh = 0; kh < 2; ++kh) {
                bf16x8 pa = as_bf16x8(*(const uint4*)&Ps[wv][qt * 16 + c][kh * 32 + hg * 8]);
#pragma unroll
                for (int dt = 0; dt < 2; ++dt)
                    O[qt][dt] = __builtin_amdgcn_mfma_f32_16x16x32_bf16(
                        pa, vf[dt][kh], O[qt][dt], 0, 0, 0);
            }
        __builtin_amdgcn_s_setprio(0);

        if (haveNext) {
            *(uint4*)&Ks[cur ^ 1][k_row][k_col] = kr;
            union { uint4 u; unsigned short s[8]; } vu; vu.u = vr;
#pragma unroll
            for (int j = 0; j < 8; ++j) Vs[cur ^ 1][k_col + j][k_row] = vu.s[j];
            __syncthreads();
        }
    }

#pragma unroll
    for (int qt = 0; qt < 2; ++qt) {
        float Ls = lrun[qt];
        Ls += __shfl_xor(Ls, 16);
        Ls += __shfl_xor(Ls, 32);
#pragma unroll
        for (int r = 0; r < 4; ++r) {
            float lr_ = __shfl(Ls, 4 * hg + r);
            int row = q0 + qt * 16 + 4 * hg + r;
            float inv = (lr_ > 0.f) ? 1.0f / lr_ : 0.f;
            if (row < NN1) {
#pragma unroll
                for (int dt = 0; dt < 2; ++dt)
                    ao[((size_t)(b * NN1 + row)) * NC + hh * NHD + dt * 16 + c]
                        = (__bf16)(O[qt][dt][r] * inv);
            }
        }
    }
}

// ---------------------------------------------------------------------------
// Kernel 3: LePE depthwise 5x5 conv, 2 rows/thread, added into bf16 ao.
// ---------------------------------------------------------------------------
__global__ __launch_bounds__(256) void lepe2_k(
    const float* __restrict__ x, const float* __restrict__ wT,
    const float* __restrict__ bias, __bf16* __restrict__ ao)
{
    int idx = blockIdx.x * 256 + threadIdx.x;
    if (idx >= NB * (NHH / 2) * NWW * (NC / 4)) return;
    int cg = idx % (NC / 4);
    int c4 = cg * 4;
    int pos = idx / (NC / 4);
    int ww = pos % NWW;
    int hp = (pos / NWW) % (NHH / 2);
    int b = pos / (NWW * (NHH / 2));
    int hh = hp * 2;

    float4 bv = *(const float4*)(bias + c4);
    float a0[2], a1[2], a2[2], a3[2];
    a0[0] = bv.x; a1[0] = bv.y; a2[0] = bv.z; a3[0] = bv.w;
    a0[1] = bv.x; a1[1] = bv.y; a2[1] = bv.z; a3[1] = bv.w;

#pragma unroll
    for (int i = 0; i < 6; ++i) {
        int y = hh + i - 2;
        bool yv = (unsigned)y < NHH;
#pragma unroll
        for (int j = 0; j < 5; ++j) {
            int xw = ww + j - 2;
            if (yv && (unsigned)xw < NWW) {
                float4 xv = *(const float4*)(x + (((size_t)b * NHH + y) * NWW + xw) * NC + c4);
                if (i < 5) {
                    float4 wv = *(const float4*)(wT + (i * 5 + j) * NC + c4);
                    a0[0] += xv.x * wv.x; a1[0] += xv.y * wv.y;
                    a2[0] += xv.z * wv.z; a3[0] += xv.w * wv.w;
                }
                if (i >= 1) {
                    float4 wv = *(const float4*)(wT + ((i - 1) * 5 + j) * NC + c4);
                    a0[1] += xv.x * wv.x; a1[1] += xv.y * wv.y;
                    a2[1] += xv.z * wv.z; a3[1] += xv.w * wv.w;
                }
            }
        }
    }

#pragma unroll
    for (int rr = 0; rr < 2; ++rr) {
        size_t m = (size_t)b * NN1 + 1 + (hh + rr) * NWW + ww;
        uint2* aop = (uint2*)(ao + m * NC + c4);
        uint2 old = *aop;
        float r0 = a0[rr] + bf2f((unsigned short)(old.x & 0xffff));
        float r1 = a1[rr] + bf2f((unsigned short)(old.x >> 16));
        float r2 = a2[rr] + bf2f((unsigned short)(old.y & 0xffff));
        float r3 = a3[rr] + bf2f((unsigned short)(old.y >> 16));
        uint2 nw; nw.x = pack2(r0, r1); nw.y = pack2(r2, r3);
        *aop = nw;
    }
}

// ---------------------------------------------------------------------------
extern "C" void kernel_launch(void* const* d_in, const int* in_sizes, int n_in,
                              void* d_out, int out_size, void* d_ws, size_t ws_size,
                              hipStream_t stream)
{
    const float* x      = (const float*)d_in[0];
    const float* cls    = (const float*)d_in[1];
    const float* qkv_w  = (const float*)d_in[2];
    const float* proj_w = (const float*)d_in[3];
    const float* proj_b = (const float*)d_in[4];
    const float* lepe_w = (const float*)d_in[5];
    const float* lepe_b = (const float*)d_in[6];
    float* out = (float*)d_out;
    char*  ws  = (char*)d_ws;

    size_t off = 0;
    __bf16* Ab    = (__bf16*)(ws + off); off += (size_t)MP2 * NC * 2;        // 6.68MB
    __bf16* wqb   = (__bf16*)(ws + off); off += (size_t)1152 * NC * 2;       // 0.88MB
    __bf16* wpb   = (__bf16*)(ws + off); off += (size_t)NC * NC * 2;         // 0.29MB
    float*  lepeT = (float*) (ws + off); off += (size_t)25 * NC * 4;         // 38KB
    __bf16* Cg    = (__bf16*)(ws + off); off += (size_t)MP2 * CST * 2;       // 20.05MB
    __bf16* aob   = (__bf16*)(ws + off); off += (size_t)MPAD * NC * 2;       // 6.39MB

    {   // prep
        prep_k<<<(P_TOT + 255) / 256, 256, 0, stream>>>(
            x, cls, qkv_w, proj_w, lepe_w, Ab, wqb, wpb, lepeT, aob);
    }
    {   // QKV GEMM: 9 tiles x 136 m-tiles = 1224 blocks
        qkv_mfma_k<<<9 * NMT, 256, 0, stream>>>(Ab, wqb, Cg);
    }
    {   // flash attention: 864 blocks
        attn_mfma_k<<<9 * NB * NHEAD, 256, 0, stream>>>(Cg, aob);
    }
    {   // LePE conv
        int total = NB * (NHW / 2) * (NC / 4);
        lepe2_k<<<(total + 255) / 256, 256, 0, stream>>>(x, lepeT, lepe_b, aob);
    }
    {   // projection GEMM
        proj_mfma_k<<<6 * 65, 256, 0, stream>>>(aob, wpb, proj_b, out);
    }
}

// Round 13
// 125.591 us; speedup vs baseline: 1.3460x; 1.3156x over previous
//
#include <hip/hip_runtime.h>
#include <math.h>

#define NB 8
#define NHH 32
#define NWW 32
#define NC 384
#define NHEAD 12
#define NHD 32
#define NN1 1025
#define NHW 1024
#define NMROWS (NB * NN1)   /* 8200 */
#define MPAD 8320           /* padded M for ao/proj (1025-based) */
#define NPB 1088            /* padded rows per batch (17*64) */
#define MP2 (NB * NPB)      /* 8704 padded global rows */
#define NMT (MP2 / 64)      /* 136 m-tiles */
#define CST 1152            /* canonical C row stride (cols) */

typedef float f32x4 __attribute__((ext_vector_type(4)));
typedef __bf16 bf16x8 __attribute__((ext_vector_type(8)));
typedef __attribute__((address_space(3))) unsigned int lds_u32;
typedef const __attribute__((address_space(1))) unsigned int glb_u32;

static __device__ __forceinline__ bf16x8 as_bf16x8(uint4 u) {
    union { uint4 a; bf16x8 b; } x; x.a = u; return x.b;
}
static __device__ __forceinline__ unsigned short bfbits(__bf16 b) {
    union { __bf16 a; unsigned short s; } u; u.a = b; return u.s;
}
static __device__ __forceinline__ float bf2f(unsigned short s) {
    union { unsigned u; float f; } x; x.u = ((unsigned)s) << 16; return x.f;
}
static __device__ __forceinline__ unsigned pack2(float a, float b) {
    return (unsigned)bfbits((__bf16)a) | ((unsigned)bfbits((__bf16)b) << 16);
}
// bijective XCD swizzle (m204)
static __device__ __forceinline__ int xcd_swz(int i, int nwg) {
    int xcd = i & 7, pos = i >> 3;
    int q = nwg >> 3, r = nwg & 7;
    return xcd * q + (xcd < r ? xcd : r) + pos;
}

// ---------------------------------------------------------------------------
// Kernel 0: prep — A=concat(cls,x) -> bf16 [8704][384] (zero pad rows),
// weights -> bf16, lepe_w transpose, zero ao pad rows.
// ---------------------------------------------------------------------------
#define P_N1 835584
#define P_N2 110592
#define P_N3 36864
#define P_N4 9600
#define P_N5 11520
#define P_TOT (P_N1 + P_N2 + P_N3 + P_N4 + P_N5)

__global__ __launch_bounds__(256) void prep_k(
    const float* __restrict__ x, const float* __restrict__ cls,
    const float* __restrict__ qkv_w, const float* __restrict__ proj_w,
    const float* __restrict__ lepe_w,
    __bf16* __restrict__ Ab, __bf16* __restrict__ wqb, __bf16* __restrict__ wpb,
    float* __restrict__ lepeT, __bf16* __restrict__ aob)
{
    int idx = blockIdx.x * 256 + threadIdx.x;
    if (idx >= P_TOT) return;
    if (idx < P_N1) {
        int e0 = idx * 4;
        int mp = e0 / NC, kk = e0 % NC;
        int b = mp / NPB, n = mp % NPB;
        float4 v = make_float4(0.f, 0.f, 0.f, 0.f);
        if (n < NN1) {
            const float* src = (n == 0) ? (cls + (size_t)b * NC + kk)
                                        : (x + ((size_t)(b * NHW + (n - 1))) * NC + kk);
            v = *(const float4*)src;
        }
        uint2 u; u.x = pack2(v.x, v.y); u.y = pack2(v.z, v.w);
        *(uint2*)(Ab + (size_t)mp * NC + kk) = u;
        return;
    }
    idx -= P_N1;
    if (idx < P_N2) {
        int e0 = idx * 4;
        float4 v = *(const float4*)(qkv_w + e0);
        uint2 u; u.x = pack2(v.x, v.y); u.y = pack2(v.z, v.w);
        *(uint2*)(wqb + e0) = u;
        return;
    }
    idx -= P_N2;
    if (idx < P_N3) {
        int e0 = idx * 4;
        float4 v = *(const float4*)(proj_w + e0);
        uint2 u; u.x = pack2(v.x, v.y); u.y = pack2(v.z, v.w);
        *(uint2*)(wpb + e0) = u;
        return;
    }
    idx -= P_N3;
    if (idx < P_N4) {
        int tap = idx / NC, cc = idx % NC;
        lepeT[tap * NC + cc] = lepe_w[cc * 25 + tap];
        return;
    }
    idx -= P_N4;
    {
        uint2 z; z.x = 0; z.y = 0;
        *(uint2*)(aob + (size_t)NMROWS * NC + idx * 4) = z;
    }
}

#define LP 72
#define QSCALE 0.25505654007f   /* 1/sqrt(32) * log2(e) */
#define CPD 136

// ---------------------------------------------------------------------------
// QKV GEMM: 64x128 tile, BK=64, 4 waves (2x2 of 32x64).  Grid 136x9 = 1224.
// Staging: global_load_lds width-16, double-buffered, linear LDS with
// XOR-swizzle applied on the per-lane GLOBAL source (m173/m201 pattern):
//   LDS word w of a tile-row holds source slot (w&7)^(row&7);
//   fragment reads use slot' = slot ^ (row&7)  -> conflict-free b128 reads.
// Output: canonical row-major C[8704][1152].
// ---------------------------------------------------------------------------
union QkvSm {
    struct { __bf16 As[2][64][64]; __bf16 Bs[2][128][64]; } g;  // 16KB+32KB
    __bf16 C[64][CPD];
};

__global__ __launch_bounds__(256) void qkv_mfma_k(
    const __bf16* __restrict__ A, const __bf16* __restrict__ W,
    __bf16* __restrict__ Cg)
{
    __shared__ QkvSm sm;
    const int tid  = threadIdx.x;
    const int lane = tid & 63;
    const int wid  = tid >> 6;
    const int wr   = wid >> 1, wc = wid & 1;
    const int c    = lane & 15, hg = lane >> 4;
    const int wg   = xcd_swz(blockIdx.x, 9 * NMT);
    const int tile = wg % 9;
    const int m0   = (wg / 9) * 64;
    const int n0   = tile * 128;

    // Pre-computed per-lane swizzled source row/col for this wave's words.
    // A: 512 words total; wave wid stages words (wid*2+j)*64 + lane, j=0,1.
    // B: 1024 words; wave stages words (wid*4+j)*64 + lane, j=0..3.
    int aw_row[2], aw_col[2];
#pragma unroll
    for (int j = 0; j < 2; ++j) {
        int word = (wid * 2 + j) * 64 + lane;
        int row = word >> 3, slot = word & 7;
        aw_row[j] = row;
        aw_col[j] = (slot ^ (row & 7)) * 8;
    }
    int bw_row[4], bw_col[4];
#pragma unroll
    for (int j = 0; j < 4; ++j) {
        int word = (wid * 4 + j) * 64 + lane;
        int row = word >> 3, slot = word & 7;
        bw_row[j] = row;
        bw_col[j] = (slot ^ (row & 7)) * 8;
    }

    f32x4 acc[2][4];
#pragma unroll
    for (int i = 0; i < 2; ++i)
#pragma unroll
        for (int j = 0; j < 4; ++j) acc[i][j] = f32x4{0.f, 0.f, 0.f, 0.f};

    __bf16* asbase = &sm.g.As[0][0][0];
    __bf16* bsbase = &sm.g.Bs[0][0][0];

    // ---- stage(buf, k0): 6 global_load_lds per wave ----
    auto stage = [&](int buf, int k0) {
#pragma unroll
        for (int j = 0; j < 2; ++j) {
            const __bf16* src = A + (size_t)(m0 + aw_row[j]) * NC + k0 + aw_col[j];
            __bf16* dst = asbase + (size_t)buf * 4096 + (wid * 2 + j) * 512;
            __builtin_amdgcn_global_load_lds((glb_u32*)src, (lds_u32*)dst, 16, 0, 0);
        }
#pragma unroll
        for (int j = 0; j < 4; ++j) {
            const __bf16* src = W + (size_t)(n0 + bw_row[j]) * NC + k0 + bw_col[j];
            __bf16* dst = bsbase + (size_t)buf * 8192 + (wid * 4 + j) * 512;
            __builtin_amdgcn_global_load_lds((glb_u32*)src, (lds_u32*)dst, 16, 0, 0);
        }
    };

    stage(0, 0);
    __syncthreads();   // drains vmcnt+lgkmcnt, barrier

    for (int t = 0; t < 6; ++t) {
        const int cur = t & 1;
        if (t < 5) stage(cur ^ 1, (t + 1) * 64);

        const __bf16* ab = asbase + (size_t)cur * 4096;
        const __bf16* bb = bsbase + (size_t)cur * 8192;
#pragma unroll
        for (int ks = 0; ks < 2; ++ks) {
            bf16x8 af[2], bfr[4];
#pragma unroll
            for (int i = 0; i < 2; ++i) {
                int row = wr * 32 + i * 16 + c;
                int slot = (ks * 4 + hg) ^ (row & 7);
                af[i] = as_bf16x8(*(const uint4*)(ab + row * 64 + slot * 8));
            }
#pragma unroll
            for (int j = 0; j < 4; ++j) {
                int row = wc * 64 + j * 16 + c;
                int slot = (ks * 4 + hg) ^ (row & 7);
                bfr[j] = as_bf16x8(*(const uint4*)(bb + row * 64 + slot * 8));
            }
            __builtin_amdgcn_s_setprio(1);
#pragma unroll
            for (int i = 0; i < 2; ++i)
#pragma unroll
                for (int j = 0; j < 4; ++j)
                    acc[i][j] = __builtin_amdgcn_mfma_f32_16x16x32_bf16(
                        af[i], bfr[j], acc[i][j], 0, 0, 0);
            __builtin_amdgcn_s_setprio(0);
        }
        if (t < 5) __syncthreads();   // drain next-tile loads + barrier
    }

    __syncthreads();   // reuse LDS as C staging
    const float qs = (tile < 3) ? QSCALE : 1.0f;
#pragma unroll
    for (int i = 0; i < 2; ++i)
#pragma unroll
        for (int r = 0; r < 4; ++r) {
            int row = wr * 32 + i * 16 + 4 * hg + r;
#pragma unroll
            for (int j = 0; j < 4; ++j)
                sm.C[row][wc * 64 + j * 16 + c] = (__bf16)(acc[i][j][r] * qs);
        }
    __syncthreads();

    // canonical write: row m0+row, cols n0..n0+127 (256B contiguous/row)
#pragma unroll
    for (int it = 0; it < 4; ++it) {
        int idx   = it * 256 + tid;
        int row   = idx >> 4;
        int chunk = idx & 15;
        uint4 u = *(const uint4*)&sm.C[row][chunk * 8];
        *(uint4*)(Cg + (size_t)(m0 + row) * CST + n0 + chunk * 8) = u;
    }
}

// ---------------------------------------------------------------------------
// proj GEMM: 128x64 tile, register-prefetched K-loop (unchanged from R12).
// ---------------------------------------------------------------------------
__global__ __launch_bounds__(256) void proj_mfma_k(
    const __bf16* __restrict__ A, const __bf16* __restrict__ W,
    const float* __restrict__ bias, float* __restrict__ out)
{
    __shared__ __bf16 As[128][LP];
    __shared__ __bf16 Bs[64][LP];
    const int tid  = threadIdx.x;
    const int lane = tid & 63;
    const int wid  = tid >> 6;
    const int wr   = wid >> 1, wc = wid & 1;
    const int c    = lane & 15, hg = lane >> 4;
    const int wg   = xcd_swz(blockIdx.x, 6 * 65);
    const int m0   = (wg / 6) * 128;
    const int n0   = (wg % 6) * 64;
    const int srow = tid >> 1;
    const int scol = (tid & 1) * 32;
    const int brow = tid >> 2;
    const int bcol = (tid & 3) * 16;

    f32x4 acc[4][2];
#pragma unroll
    for (int i = 0; i < 4; ++i)
#pragma unroll
        for (int j = 0; j < 2; ++j) acc[i][j] = f32x4{0.f, 0.f, 0.f, 0.f};

    uint4 a4[4], b4[2];
#pragma unroll
    for (int s = 0; s < 4; ++s)
        a4[s] = *(const uint4*)(A + (size_t)(m0 + srow) * NC + scol + s * 8);
#pragma unroll
    for (int s = 0; s < 2; ++s)
        b4[s] = *(const uint4*)(W + (size_t)(n0 + brow) * NC + bcol + s * 8);

    for (int k0 = 0; k0 < NC; k0 += 64) {
        __syncthreads();
#pragma unroll
        for (int s = 0; s < 4; ++s) *(uint4*)&As[srow][scol + s * 8] = a4[s];
#pragma unroll
        for (int s = 0; s < 2; ++s) *(uint4*)&Bs[brow][bcol + s * 8] = b4[s];
        __syncthreads();
        if (k0 + 64 < NC) {
#pragma unroll
            for (int s = 0; s < 4; ++s)
                a4[s] = *(const uint4*)(A + (size_t)(m0 + srow) * NC + k0 + 64 + scol + s * 8);
#pragma unroll
            for (int s = 0; s < 2; ++s)
                b4[s] = *(const uint4*)(W + (size_t)(n0 + brow) * NC + k0 + 64 + bcol + s * 8);
        }
#pragma unroll
        for (int ks = 0; ks < 2; ++ks) {
            bf16x8 af[4], bfr[2];
#pragma unroll
            for (int i = 0; i < 4; ++i)
                af[i] = as_bf16x8(*(const uint4*)&As[wr * 64 + i * 16 + c][ks * 32 + hg * 8]);
#pragma unroll
            for (int j = 0; j < 2; ++j)
                bfr[j] = as_bf16x8(*(const uint4*)&Bs[wc * 32 + j * 16 + c][ks * 32 + hg * 8]);
#pragma unroll
            for (int i = 0; i < 4; ++i)
#pragma unroll
                for (int j = 0; j < 2; ++j)
                    acc[i][j] = __builtin_amdgcn_mfma_f32_16x16x32_bf16(
                        af[i], bfr[j], acc[i][j], 0, 0, 0);
        }
    }

#pragma unroll
    for (int i = 0; i < 4; ++i)
#pragma unroll
        for (int r = 0; r < 4; ++r) {
            int m = m0 + wr * 64 + i * 16 + 4 * hg + r;
            if (m >= NMROWS) continue;
            int b = m / NN1, n = m % NN1;
            float* dstrow = (n == 0)
                ? (out + (size_t)NB * NHW * NC + (size_t)b * NC)
                : (out + ((size_t)(b * NHW) + (n - 1)) * NC);
#pragma unroll
            for (int j = 0; j < 2; ++j) {
                int col = n0 + wc * 32 + j * 16 + c;
                dstrow[col] = acc[i][j][r] + bias[col];
            }
        }
}

// ---------------------------------------------------------------------------
// Kernel 2: bf16-MFMA flash attention reading canonical C (unchanged R12).
// ---------------------------------------------------------------------------
#define KC 64
#define KPAD 40
#define VPAD 72
#define PPAD 72
#define NCH ((NN1 + KC - 1) / KC)   /* 17 */

__global__ __launch_bounds__(256) void attn_mfma_k(
    const __bf16* __restrict__ Cg, __bf16* __restrict__ ao)
{
    __shared__ unsigned short Ks[2][KC][KPAD];
    __shared__ unsigned short Vs[2][32][VPAD];
    __shared__ unsigned short Ps[4][32][PPAD];

    const int wg    = xcd_swz(blockIdx.x, 9 * NB * NHEAD);
    const int qtile = wg % 9;
    const int bh    = wg / 9;
    const int b     = bh / NHEAD;
    const int hh    = bh % NHEAD;
    const int tid   = threadIdx.x;
    const int wv    = tid >> 6;
    const int lane  = tid & 63;
    const int c     = lane & 15;
    const int hg    = lane >> 4;
    const int q0    = qtile * 128 + wv * 32;
    const size_t MBp = (size_t)b * NPB;

    const __bf16* qb = Cg + hh * 32;
    const __bf16* kb = Cg + 384 + hh * 32;
    const __bf16* vb = Cg + 768 + hh * 32;

    uint4 zero4 = make_uint4(0, 0, 0, 0);
    bf16x8 qf[2];
#pragma unroll
    for (int qt = 0; qt < 2; ++qt) {
        int row = q0 + qt * 16 + c;
        uint4 u = (row < NN1)
            ? *(const uint4*)(qb + (MBp + row) * CST + hg * 8) : zero4;
        qf[qt] = as_bf16x8(u);
    }

    f32x4 O[2][2];
#pragma unroll
    for (int qt = 0; qt < 2; ++qt)
#pragma unroll
        for (int dt = 0; dt < 2; ++dt) O[qt][dt] = f32x4{0.f, 0.f, 0.f, 0.f};
    float lrun[2] = {0.f, 0.f};

    const int k_row = tid >> 2;
    const int k_col = (tid & 3) * 8;

    uint4 kr = *(const uint4*)(kb + (MBp + k_row) * CST + k_col);
    uint4 vr = *(const uint4*)(vb + (MBp + k_row) * CST + k_col);
    *(uint4*)&Ks[0][k_row][k_col] = kr;
    {
        union { uint4 u; unsigned short s[8]; } vu; vu.u = vr;
#pragma unroll
        for (int j = 0; j < 8; ++j) Vs[0][k_col + j][k_row] = vu.s[j];
    }
    __syncthreads();

    for (int t = 0; t < NCH; ++t) {
        const int kt0 = t * KC;
        const int cur = t & 1;
        const bool haveNext = (t + 1 < NCH);
        if (haveNext) {
            kr = *(const uint4*)(kb + (MBp + kt0 + KC + k_row) * CST + k_col);
            vr = *(const uint4*)(vb + (MBp + kt0 + KC + k_row) * CST + k_col);
        }
        const bool full = (kt0 + KC <= NN1);

        bf16x8 kf[4];
#pragma unroll
        for (int kt = 0; kt < 4; ++kt)
            kf[kt] = as_bf16x8(*(const uint4*)&Ks[cur][kt * 16 + c][hg * 8]);

#pragma unroll
        for (int qt = 0; qt < 2; ++qt) {
            f32x4 Sf[4];
            __builtin_amdgcn_s_setprio(1);
#pragma unroll
            for (int kt = 0; kt < 4; ++kt)
                Sf[kt] = __builtin_amdgcn_mfma_f32_16x16x32_bf16(
                    kf[kt], qf[qt], f32x4{0.f, 0.f, 0.f, 0.f}, 0, 0, 0);
            __builtin_amdgcn_s_setprio(0);

            if (!full) {
#pragma unroll
                for (int kt = 0; kt < 4; ++kt)
#pragma unroll
                    for (int r = 0; r < 4; ++r) {
                        int key = kt0 + kt * 16 + 4 * hg + r;
                        if (key >= NN1) Sf[kt][r] = -3.0e38f;
                    }
            }
            float psum = 0.f;
#pragma unroll
            for (int kt = 0; kt < 4; ++kt) {
                float p0 = exp2f(Sf[kt][0]);
                float p1 = exp2f(Sf[kt][1]);
                float p2 = exp2f(Sf[kt][2]);
                float p3 = exp2f(Sf[kt][3]);
                psum += (p0 + p1) + (p2 + p3);
                uint2 w; w.x = pack2(p0, p1); w.y = pack2(p2, p3);
                *(uint2*)&Ps[wv][qt * 16 + c][kt * 16 + 4 * hg] = w;
            }
            lrun[qt] += psum;
        }

        bf16x8 vf[2][2];
#pragma unroll
        for (int dt = 0; dt < 2; ++dt)
#pragma unroll
            for (int kh = 0; kh < 2; ++kh)
                vf[dt][kh] = as_bf16x8(*(const uint4*)&Vs[cur][dt * 16 + c][kh * 32 + hg * 8]);

        __builtin_amdgcn_s_setprio(1);
#pragma unroll
        for (int qt = 0; qt < 2; ++qt)
#pragma unroll
            for (int kh = 0; kh < 2; ++kh) {
                bf16x8 pa = as_bf16x8(*(const uint4*)&Ps[wv][qt * 16 + c][kh * 32 + hg * 8]);
#pragma unroll
                for (int dt = 0; dt < 2; ++dt)
                    O[qt][dt] = __builtin_amdgcn_mfma_f32_16x16x32_bf16(
                        pa, vf[dt][kh], O[qt][dt], 0, 0, 0);
            }
        __builtin_amdgcn_s_setprio(0);

        if (haveNext) {
            *(uint4*)&Ks[cur ^ 1][k_row][k_col] = kr;
            union { uint4 u; unsigned short s[8]; } vu; vu.u = vr;
#pragma unroll
            for (int j = 0; j < 8; ++j) Vs[cur ^ 1][k_col + j][k_row] = vu.s[j];
            __syncthreads();
        }
    }

#pragma unroll
    for (int qt = 0; qt < 2; ++qt) {
        float Ls = lrun[qt];
        Ls += __shfl_xor(Ls, 16);
        Ls += __shfl_xor(Ls, 32);
#pragma unroll
        for (int r = 0; r < 4; ++r) {
            float lr_ = __shfl(Ls, 4 * hg + r);
            int row = q0 + qt * 16 + 4 * hg + r;
            float inv = (lr_ > 0.f) ? 1.0f / lr_ : 0.f;
            if (row < NN1) {
#pragma unroll
                for (int dt = 0; dt < 2; ++dt)
                    ao[((size_t)(b * NN1 + row)) * NC + hh * NHD + dt * 16 + c]
                        = (__bf16)(O[qt][dt][r] * inv);
            }
        }
    }
}

// ---------------------------------------------------------------------------
// Kernel 3: LePE depthwise 5x5 conv, 2 rows/thread, added into bf16 ao.
// ---------------------------------------------------------------------------
__global__ __launch_bounds__(256) void lepe2_k(
    const float* __restrict__ x, const float* __restrict__ wT,
    const float* __restrict__ bias, __bf16* __restrict__ ao)
{
    int idx = blockIdx.x * 256 + threadIdx.x;
    if (idx >= NB * (NHH / 2) * NWW * (NC / 4)) return;
    int cg = idx % (NC / 4);
    int c4 = cg * 4;
    int pos = idx / (NC / 4);
    int ww = pos % NWW;
    int hp = (pos / NWW) % (NHH / 2);
    int b = pos / (NWW * (NHH / 2));
    int hh = hp * 2;

    float4 bv = *(const float4*)(bias + c4);
    float a0[2], a1[2], a2[2], a3[2];
    a0[0] = bv.x; a1[0] = bv.y; a2[0] = bv.z; a3[0] = bv.w;
    a0[1] = bv.x; a1[1] = bv.y; a2[1] = bv.z; a3[1] = bv.w;

#pragma unroll
    for (int i = 0; i < 6; ++i) {
        int y = hh + i - 2;
        bool yv = (unsigned)y < NHH;
#pragma unroll
        for (int j = 0; j < 5; ++j) {
            int xw = ww + j - 2;
            if (yv && (unsigned)xw < NWW) {
                float4 xv = *(const float4*)(x + (((size_t)b * NHH + y) * NWW + xw) * NC + c4);
                if (i < 5) {
                    float4 wv = *(const float4*)(wT + (i * 5 + j) * NC + c4);
                    a0[0] += xv.x * wv.x; a1[0] += xv.y * wv.y;
                    a2[0] += xv.z * wv.z; a3[0] += xv.w * wv.w;
                }
                if (i >= 1) {
                    float4 wv = *(const float4*)(wT + ((i - 1) * 5 + j) * NC + c4);
                    a0[1] += xv.x * wv.x; a1[1] += xv.y * wv.y;
                    a2[1] += xv.z * wv.z; a3[1] += xv.w * wv.w;
                }
            }
        }
    }

#pragma unroll
    for (int rr = 0; rr < 2; ++rr) {
        size_t m = (size_t)b * NN1 + 1 + (hh + rr) * NWW + ww;
        uint2* aop = (uint2*)(ao + m * NC + c4);
        uint2 old = *aop;
        float r0 = a0[rr] + bf2f((unsigned short)(old.x & 0xffff));
        float r1 = a1[rr] + bf2f((unsigned short)(old.x >> 16));
        float r2 = a2[rr] + bf2f((unsigned short)(old.y & 0xffff));
        float r3 = a3[rr] + bf2f((unsigned short)(old.y >> 16));
        uint2 nw; nw.x = pack2(r0, r1); nw.y = pack2(r2, r3);
        *aop = nw;
    }
}

// ---------------------------------------------------------------------------
extern "C" void kernel_launch(void* const* d_in, const int* in_sizes, int n_in,
                              void* d_out, int out_size, void* d_ws, size_t ws_size,
                              hipStream_t stream)
{
    const float* x      = (const float*)d_in[0];
    const float* cls    = (const float*)d_in[1];
    const float* qkv_w  = (const float*)d_in[2];
    const float* proj_w = (const float*)d_in[3];
    const float* proj_b = (const float*)d_in[4];
    const float* lepe_w = (const float*)d_in[5];
    const float* lepe_b = (const float*)d_in[6];
    float* out = (float*)d_out;
    char*  ws  = (char*)d_ws;

    size_t off = 0;
    __bf16* Ab    = (__bf16*)(ws + off); off += (size_t)MP2 * NC * 2;
    __bf16* wqb   = (__bf16*)(ws + off); off += (size_t)1152 * NC * 2;
    __bf16* wpb   = (__bf16*)(ws + off); off += (size_t)NC * NC * 2;
    float*  lepeT = (float*) (ws + off); off += (size_t)25 * NC * 4;
    __bf16* Cg    = (__bf16*)(ws + off); off += (size_t)MP2 * CST * 2;
    __bf16* aob   = (__bf16*)(ws + off); off += (size_t)MPAD * NC * 2;

    {   // prep
        prep_k<<<(P_TOT + 255) / 256, 256, 0, stream>>>(
            x, cls, qkv_w, proj_w, lepe_w, Ab, wqb, wpb, lepeT, aob);
    }
    {   // QKV GEMM: gload_lds + swizzle, 1224 blocks
        qkv_mfma_k<<<9 * NMT, 256, 0, stream>>>(Ab, wqb, Cg);
    }
    {   // flash attention: 864 blocks
        attn_mfma_k<<<9 * NB * NHEAD, 256, 0, stream>>>(Cg, aob);
    }
    {   // LePE conv
        int total = NB * (NHW / 2) * (NC / 4);
        lepe2_k<<<(total + 255) / 256, 256, 0, stream>>>(x, lepeT, lepe_b, aob);
    }
    {   // projection GEMM
        proj_mfma_k<<<6 * 65, 256, 0, stream>>>(aob, wpb, proj_b, out);
    }
}